// Round 6
// baseline (494.724 us; speedup 1.0000x reference)
//
#include <hip/hip_runtime.h>

// ---------------------------------------------------------------------------
// DecoderBlock: x = LN1(x + SelfAttn(x));  x = LN2(x + CrossAttn(x, mem));
//               x = LN3(x + W2·relu(W1·x + b1) + b2)
// B=2, N=2048, M=1024, D=1024, H=16, Dh=64, FF=4096.
// R18 = R16 GEMM cores (R17's store-pattern change reverted: WRITE_SIZE
//   proved invariant 62.3->63.0 MB, 8B-segment stores regressed +12us)
//   + R17 attn keepers (Q-prescale, v_perm packing; attn 50.4 -> <48.8)
//   + occupancy experiment: selfO/crossQ/crossO/FFN2 -> gemm_bt<128,128>
//     SK=1 (256-block grids, 32KB LDS, 16 waves/CU vs gemm8's 8).
//     FFN2(128^2,K=4096) vs FFN1(256^2 gemm8,K=1024): same FLOPs, one
//     profile = direct A/B of the occupancy hypothesis.
//   + split-K eliminated everywhere -> saves 80MB partial write+read,
//     LN deltas ND=1.
// ---------------------------------------------------------------------------

typedef __attribute__((ext_vector_type(8))) short bf16x8;   // 8 bf16 (4 VGPRs)
typedef __attribute__((ext_vector_type(4))) float f32x4;

__device__ __forceinline__ unsigned short f2bf(float f) {
    union { float f; unsigned int u; } v; v.f = f;
    unsigned int r = v.u + 0x7fffu + ((v.u >> 16) & 1u);   // RNE
    return (unsigned short)(r >> 16);
}
__device__ __forceinline__ float bf2f(unsigned short u) {
    union { unsigned int u; float f; } v; v.u = (unsigned int)u << 16;
    return v.f;
}
__device__ __forceinline__ unsigned int fbits(float f) {
    union { float f; unsigned int u; } v; v.f = f;
    return v.u;
}

// ------------------- fused fp32->bf16 conversion + bias concat -------------
struct ConvArgs {
    const float* src[12];
    unsigned short* dst[12];
    int blk_ofs[13];
    int n4[12];
    const float* bq; const float* bk; const float* bv;
    const float* ck; const float* cv;
    float* bqkv; float* bkvc;
};
__global__ __launch_bounds__(256) void conv_multi(ConvArgs a)
{
    int bid = blockIdx.x;
    if (bid >= a.blk_ofs[12]) {                  // bias-concat tail
        int i = (bid - a.blk_ofs[12]) * 256 + threadIdx.x;   // 0..5119
        if (i < 1024)       a.bqkv[i] = a.bq[i];
        else if (i < 2048)  a.bqkv[i] = a.bk[i - 1024];
        else if (i < 3072)  a.bqkv[i] = a.bv[i - 2048];
        else if (i < 4096)  a.bkvc[i - 3072] = a.ck[i - 3072];
        else if (i < 5120)  a.bkvc[i - 3072] = a.cv[i - 4096];
        return;
    }
    int s = 0;
#pragma unroll
    for (int t = 0; t < 12; ++t) if (bid >= a.blk_ofs[t + 1]) s = t + 1;
    int i = (bid - a.blk_ofs[s]) * 256 + threadIdx.x;
    if (i >= a.n4[s]) return;
    float4 v = ((const float4*)a.src[s])[i];
    ushort4 o;
    o.x = f2bf(v.x); o.y = f2bf(v.y); o.z = f2bf(v.z); o.w = f2bf(v.w);
    ((ushort4*)a.dst[s])[i] = o;
}

// --------------------------- bf16 GEMM core (2-phase) ----------------------
// R18: used at <128,128> for selfO / crossQ / crossO / FFN2 (256 blocks,
// 32KB LDS -> ~4 blocks/CU = 16 waves/CU). R16 epilogue (scalar stores).
template<int TM, int TN, int EPI, int SK>
__device__ __forceinline__ void gemm_body(
    unsigned short (*As)[64], unsigned short (*Bs)[64],
    const unsigned short* __restrict__ A, const unsigned short* __restrict__ W,
    const float* __restrict__ bias, unsigned short* __restrict__ out,
    int K, int Ncols, long slice_stride, int bid, int gx, int zslice)
{
    constexpr int AI = TM / 32;
    constexpr int BJ = TN / 32;

    const int tid  = threadIdx.x;
    const int lane = tid & 63;
    const int wave = tid >> 6;
    const int qd   = lane >> 4;
    const int l15  = lane & 15;
    const int wm   = (wave >> 1) * (TM / 2);
    const int wn   = (wave & 1) * (TN / 2);

    const int gpg = 8 * gx;                       // GROUP_M=8 swizzle
    const long m0 = (long)((bid / gpg) * 8 + (bid & 7)) * TM;
    const long n0 = (long)((bid % gpg) >> 3) * TN;

    f32x4 acc[AI][BJ] = {};

    const int srow = lane >> 3;
    const int scol = (((lane & 7) ^ srow)) * 8;   // XOR-swizzled group
    const unsigned short* Ag = A + (m0 + wave * (8 * AI) + srow) * (long)K + scol;
    const unsigned short* Wg = W + (n0 + wave * (8 * BJ) + srow) * (long)K + scol;

    const int ksl   = K / SK;
    const int kbase = (SK > 1) ? zslice * ksl : 0;

    for (int k0 = kbase; k0 < kbase + ksl; k0 += 64) {
#pragma unroll
        for (int c = 0; c < AI; ++c)
            __builtin_amdgcn_global_load_lds(
                (const __attribute__((address_space(1))) unsigned int*)(Ag + (long)c * 8 * K + k0),
                (__attribute__((address_space(3))) unsigned int*)((char*)&As[0][0] + (wave * AI + c) * 1024),
                16, 0, 0);
#pragma unroll
        for (int c = 0; c < BJ; ++c)
            __builtin_amdgcn_global_load_lds(
                (const __attribute__((address_space(1))) unsigned int*)(Wg + (long)c * 8 * K + k0),
                (__attribute__((address_space(3))) unsigned int*)((char*)&Bs[0][0] + (wave * BJ + c) * 1024),
                16, 0, 0);
        __syncthreads();
#pragma unroll
        for (int kk = 0; kk < 64; kk += 32) {
            const int pg = ((((kk >> 3) + qd)) ^ (l15 & 7)) * 8;  // de-swizzle
            bf16x8 af[AI], bw[BJ];
#pragma unroll
            for (int i = 0; i < AI; ++i)
                af[i] = *(const bf16x8*)&As[wm + i * 16 + l15][pg];
#pragma unroll
            for (int j = 0; j < BJ; ++j)
                bw[j] = *(const bf16x8*)&Bs[wn + j * 16 + l15][pg];
#pragma unroll
            for (int i = 0; i < AI; ++i)
#pragma unroll
                for (int j = 0; j < BJ; ++j)
                    acc[i][j] = __builtin_amdgcn_mfma_f32_16x16x32_bf16(
                        af[i], bw[j], acc[i][j], 0, 0, 0);
        }
        __syncthreads();
    }

    // epilogue. C/D layout: col = lane&15, row = quad*4 + reg  [m89-verified]
    unsigned short* op = out + ((SK > 1) ? (long)zslice * slice_stride : 0);
#pragma unroll
    for (int j = 0; j < BJ; ++j) {
        long col = n0 + wn + j * 16 + l15;
        float bv = (SK == 1 || zslice == 0) ? bias[col] : 0.f;
#pragma unroll
        for (int i = 0; i < AI; ++i) {
#pragma unroll
            for (int r = 0; r < 4; ++r) {
                long row = m0 + wm + i * 16 + qd * 4 + r;
                float v = acc[i][j][r] + bv;
                if (EPI == 1) v = (v > 0.f) ? v : 0.f;
                op[row * Ncols + col] = f2bf(v);
            }
        }
    }
}

template<int TM, int TN, int EPI, int SK>
__global__ __launch_bounds__(256) void gemm_bt(
    const unsigned short* __restrict__ A, const unsigned short* __restrict__ W,
    const float* __restrict__ bias, unsigned short* __restrict__ out,
    int K, int Ncols, long slice_stride)
{
    __shared__ unsigned short As[TM][64];
    __shared__ unsigned short Bs[TN][64];
    const int bid = blockIdx.y * gridDim.x + blockIdx.x;
    gemm_body<TM, TN, EPI, SK>(As, Bs, A, W, bias, out, K, Ncols, slice_stride,
                               bid, gridDim.x, (int)blockIdx.z);
}

// --------------------------- 256^2 2-barrier GEMM --------------------------
// (R16 version.) BM=BN=256, BK=64, 512 thr (8 waves, 2M x 4N). LDS 128 KiB
// double-buffered; XOR-swizzle staging source + reads; per K-group:
// {pre-stage A(g+1)-tails | reads+MFMA i-low | MID bar | stage g+2 into
//  dead slots | reads+MFMA i-high (B in regs) | vmcnt(6) + END bar}.
template<int EPI, int SK>
__device__ __forceinline__ void gemm8_body(
    unsigned short* Ab, unsigned short* Bb,
    const unsigned short* __restrict__ A, const unsigned short* __restrict__ W,
    const float* __restrict__ bias, unsigned short* __restrict__ out,
    int K, int Ncols, long slice_stride, int mb, int nb, int zslice)
{
    const int tid  = threadIdx.x;       // 0..511
    const int lane = tid & 63;
    const int wave = tid >> 6;          // 0..7
    const int qd   = lane >> 4;
    const int l15  = lane & 15;
    const int wm   = (wave >> 2) * 128; // 2 M-waves
    const int wn   = (wave & 3) * 64;   // 4 N-waves

    const long m0 = (long)mb * 256;
    const long n0 = (long)nb * 256;

    const int ksl   = K / SK;
    const int kbase = (SK > 1) ? zslice * ksl : 0;
    const int NG    = ksl / 64;         // 16 for all call sites here

    f32x4 acc[8][4] = {};

    const int srow = tid >> 3;                       // 0..63
    const int sgrp = ((tid & 7) ^ (srow & 7)) * 8;
    const unsigned short* Ag = A + (m0 + srow) * (long)K + kbase + sgrp;
    const unsigned short* Wg = W + (n0 + srow) * (long)K + kbase + sgrp;

    auto stA = [&](int db, int r0, int kt) {
        __builtin_amdgcn_global_load_lds(
            (const __attribute__((address_space(1))) unsigned int*)(Ag + (long)r0 * K + kt * 64),
            (__attribute__((address_space(3))) unsigned int*)(Ab + db * 16384 + r0 * 64 + wave * 512),
            16, 0, 0);
    };
    auto stB = [&](int db, int r0, int kt) {
        __builtin_amdgcn_global_load_lds(
            (const __attribute__((address_space(1))) unsigned int*)(Wg + (long)r0 * K + kt * 64),
            (__attribute__((address_space(3))) unsigned int*)(Bb + db * 16384 + r0 * 64 + wave * 512),
            16, 0, 0);
    };
    auto rdA = [&](int db, int row, int kk) -> bf16x8 {
        const int p = (((kk << 2) + qd) ^ (l15 & 7)) << 3;
        return *(const bf16x8*)(Ab + db * 16384 + row * 64 + p);
    };
    auto rdB = [&](int db, int row, int kk) -> bf16x8 {
        const int p = (((kk << 2) + qd) ^ (l15 & 7)) << 3;
        return *(const bf16x8*)(Bb + db * 16384 + row * 64 + p);
    };

    // ---- prologue: tile0 full (8) -> buf0; tile1 B + A-heads (6) -> buf1 --
#pragma unroll
    for (int h = 0; h < 4; ++h) stA(0, h * 64, 0);
#pragma unroll
    for (int h = 0; h < 4; ++h) stB(0, h * 64, 0);
    if (NG > 1) {
#pragma unroll
        for (int h = 0; h < 4; ++h) stB(1, h * 64, 1);
        stA(1, 0, 1); stA(1, 128, 1);
        asm volatile("s_waitcnt vmcnt(6)" ::: "memory");   // tile0 resident
    } else {
        asm volatile("s_waitcnt vmcnt(0)" ::: "memory");
    }
    __builtin_amdgcn_s_barrier();

    for (int g = 0; g < NG; ++g) {
        const int db = g & 1, ob = db ^ 1;
        bf16x8 af[4][2], bw[4][2];

        if (g + 1 < NG) { stA(ob, 64, g + 1); stA(ob, 192, g + 1); }

        // ---- h1: i-low half ----
#pragma unroll
        for (int i = 0; i < 4; ++i)
#pragma unroll
            for (int kk = 0; kk < 2; ++kk)
                af[i][kk] = rdA(db, wm + i * 16 + l15, kk);
#pragma unroll
        for (int j = 0; j < 4; ++j)
#pragma unroll
            for (int kk = 0; kk < 2; ++kk)
                bw[j][kk] = rdB(db, wn + j * 16 + l15, kk);
        __builtin_amdgcn_s_setprio(1);
#pragma unroll
        for (int i = 0; i < 4; ++i)
#pragma unroll
            for (int j = 0; j < 4; ++j) {
                acc[i][j] = __builtin_amdgcn_mfma_f32_16x16x32_bf16(af[i][0], bw[j][0], acc[i][j], 0, 0, 0);
                acc[i][j] = __builtin_amdgcn_mfma_f32_16x16x32_bf16(af[i][1], bw[j][1], acc[i][j], 0, 0, 0);
            }
        __builtin_amdgcn_s_setprio(0);
        __builtin_amdgcn_s_barrier();                      // MID

        if (g + 2 < NG) {
#pragma unroll
            for (int h = 0; h < 4; ++h) stB(db, h * 64, g + 2);
            stA(db, 0, g + 2); stA(db, 128, g + 2);
        }

        // ---- h2: i-high half (bw in regs) ----
#pragma unroll
        for (int i = 0; i < 4; ++i)
#pragma unroll
            for (int kk = 0; kk < 2; ++kk)
                af[i][kk] = rdA(db, wm + 64 + i * 16 + l15, kk);
        __builtin_amdgcn_s_setprio(1);
#pragma unroll
        for (int i = 0; i < 4; ++i)
#pragma unroll
            for (int j = 0; j < 4; ++j) {
                acc[4 + i][j] = __builtin_amdgcn_mfma_f32_16x16x32_bf16(af[i][0], bw[j][0], acc[4 + i][j], 0, 0, 0);
                acc[4 + i][j] = __builtin_amdgcn_mfma_f32_16x16x32_bf16(af[i][1], bw[j][1], acc[4 + i][j], 0, 0, 0);
            }
        __builtin_amdgcn_s_setprio(0);

        if (g + 2 < NG)      { asm volatile("s_waitcnt vmcnt(6)" ::: "memory"); }
        else if (g + 1 < NG) { asm volatile("s_waitcnt vmcnt(0)" ::: "memory"); }
        __builtin_amdgcn_s_barrier();
    }

    // ---- epilogue. C/D layout: col = lane&15, row = quad*4 + reg ----
    unsigned short* op = out + ((SK > 1) ? (long)zslice * slice_stride : 0);
#pragma unroll
    for (int j = 0; j < 4; ++j) {
        long col = n0 + wn + j * 16 + l15;
        float bv = (SK == 1 || zslice == 0) ? bias[col] : 0.f;
#pragma unroll
        for (int i = 0; i < 8; ++i) {
#pragma unroll
            for (int r = 0; r < 4; ++r) {
                long row = m0 + wm + (i >> 2) * 64 + (i & 3) * 16 + qd * 4 + r;
                float v = acc[i][j][r] + bv;
                if (EPI == 1) v = (v > 0.f) ? v : 0.f;
                op[row * Ncols + col] = f2bf(v);
            }
        }
    }
}

// MODE 1: FFN1 16m x 16n, per-XCD region 4m x 8n.
template<int EPI, int SK, int MODE>
__global__ __launch_bounds__(512) void gemm8_bt(
    const unsigned short* __restrict__ A, const unsigned short* __restrict__ W,
    const float* __restrict__ bias, unsigned short* __restrict__ out,
    int K, int Ncols, long slice_stride)
{
    extern __shared__ unsigned short smem[];
    const int bid = blockIdx.x;
    const int x = bid & 7;              // assumed hw XCD (round-robin)
    const int s = bid >> 3;             // 0..31
    int mb, nb, z = 0;
    if (MODE == 1) {
        mb = (x >> 1) * 4 + (s & 3);
        nb = (x & 1) * 8 + (s >> 2);
    } else {
        z  = x >> 1;
        mb = (x & 1) * 8 + (s & 7);
        nb = s >> 3;
    }
    gemm8_body<EPI, SK>(smem, smem + 32768, A, W, bias, out, K, Ncols,
                        slice_stride, mb, nb, z);
}

// selfQKV (192 blk, region 4m x 6n) + crossKV (64 blk, region 2m x 4n).
__global__ __launch_bounds__(512) void gemm8_dual(
    const unsigned short* A0, const unsigned short* W0, const float* b0,
    unsigned short* o0, int K0, int N0,
    const unsigned short* A1, const unsigned short* W1, const float* b1,
    unsigned short* o1, int K1, int N1)
{
    extern __shared__ unsigned short smem[];
    const int bid = blockIdx.x;
    const int x = bid & 7;
    const int s = bid >> 3;             // 0..31
    if (s < 24) {
        const int mb = (x >> 1) * 4 + (s & 3);
        const int nb = (x & 1) * 6 + (s >> 2);
        gemm8_body<0, 1>(smem, smem + 32768, A0, W0, b0, o0, K0, N0, 0, mb, nb, 0);
    } else {
        const int t = s - 24;           // 0..7
        const int mb = (x >> 1) * 2 + (t & 1);
        const int nb = (x & 1) * 4 + (t >> 1);
        gemm8_body<0, 1>(smem, smem + 32768, A1, W1, b1, o1, K1, N1, 0, mb, nb, 0);
    }
}

// --------------------------- flash attention (MFMA, 4-wave, 64q) -----------
// Ks/Vs/Ps: [64] XOR group-swizzle (store+read), 0 bank conflicts (R14).
// R17 keepers: Q pre-scaled by SCL (exp2 direct), v_perm packing.
__global__ __launch_bounds__(256) void attn_kernel(
    const unsigned short* __restrict__ Qb, int q_stride,
    const unsigned short* __restrict__ KVb, int kv_stride, int koff, int voff,
    unsigned short* __restrict__ O,
    int Nq, int Mk, int causal)
{
    __shared__ unsigned short Ks[64][64];
    __shared__ unsigned short Vs[64][64];
    __shared__ unsigned short Ps[4][16][64];

    const int tid  = threadIdx.x;
    const int lane = tid & 63;
    const int wave = tid >> 6;
    const int qd   = lane >> 4;
    const int l15  = lane & 15;
    const int l7   = l15 & 7;
    const int h    = blockIdx.y;
    const int b    = blockIdx.z;
    int jq = blockIdx.x;
    if (causal && (b & 1)) jq = gridDim.x - 1 - jq;
    const int q0 = jq * 64;
    const int tb = q0 + wave * 16;

    const float SCL = 0.125f * 1.44269504f;

    bf16x8 aq0, aq1;
    {
        const unsigned short* qp =
            Qb + (long)(b * Nq + tb + l15) * q_stride + h * 64 + qd * 8;
        aq0 = *(const bf16x8*)qp;
        aq1 = *(const bf16x8*)(qp + 32);
#pragma unroll
        for (int j = 0; j < 8; ++j) {
            aq0[j] = (short)f2bf(bf2f((unsigned short)aq0[j]) * SCL);
            aq1[j] = (short)f2bf(bf2f((unsigned short)aq1[j]) * SCL);
        }
    }

    float lpart[4] = {};
    f32x4 oacc[4] = {};

    const int krow  = tid >> 3;
    const int kcol  = (tid & 7) * 8;                     // global K col
    const int kcolS = (((tid & 7) ^ (krow & 7))) * 8;    // swizzled LDS col
    const int vj   = tid & 31;
    const int va_k = (vj & 15) + ((vj & 16) << 1);
    const int vfg  = (tid >> 5) * 8;
    const int vpc  = (va_k & 15) * 4 + (va_k >> 4);      // even => u32-aligned

    const unsigned short* Kg = KVb + (long)b * Mk * kv_stride + koff + h * 64;
    const unsigned short* Vg = KVb + (long)b * Mk * kv_stride + voff + h * 64;

    bf16x8 kr0, kr1, vra, vrb;
    auto prefetch = [&](int k0) {
        kr0 = *(const bf16x8*)(Kg + (long)(k0 + krow) * kv_stride + kcol);
        kr1 = *(const bf16x8*)(Kg + (long)(k0 + krow + 32) * kv_stride + kcol);
        const unsigned short* v0 = Vg + (long)(k0 + va_k) * kv_stride + vfg;
        vra = *(const bf16x8*)v0;
        vrb = *(const bf16x8*)(v0 + 16 * kv_stride);
    };

    const int nk = causal ? (q0 + 64) : Mk;
    prefetch(0);

    for (int k0 = 0; k0 < nk; k0 += 64) {
        __syncthreads();
        *(bf16x8*)&Ks[krow][kcolS]      = kr0;
        *(bf16x8*)&Ks[krow + 32][kcolS] = kr1;
        {
            const unsigned int* pa = (const unsigned int*)&vra;
            const unsigned int* pb = (const unsigned int*)&vrb;
#pragma unroll
            for (int w2 = 0; w2 < 4; ++w2) {
                unsigned int d0 = __builtin_amdgcn_perm(pb[w2], pa[w2], 0x05040100u);
                unsigned int d1 = __builtin_amdgcn_perm(pb[w2], pa[w2], 0x07060302u);
                const int r0 = vfg + 2 * w2, r1 = r0 + 1;
                *(unsigned int*)&Vs[r0][vpc ^ ((r0 & 7) << 3)] = d0;
                *(unsigned int*)&Vs[r1][vpc ^ ((r1 & 7) << 3)] = d1;
            }
        }
        if (k0 + 64 < nk) prefetch(k0 + 64);
        __syncthreads();

        if (!causal || (k0 <= tb + 15)) {
            bf16x8 bk[4][2];
#pragma unroll
            for (int kt = 0; kt < 4; ++kt)
#pragma unroll
                for (int c = 0; c < 2; ++c)
                    bk[kt][c] = *(const bf16x8*)&Ks[kt * 16 + l15][((c * 4 + qd) ^ l7) * 8];
            f32x4 s[4];
#pragma unroll
            for (int kt = 0; kt < 4; ++kt) {
                f32x4 z = {};
                z = __builtin_amdgcn_mfma_f32_16x16x32_bf16(aq0, bk[kt][0], z, 0, 0, 0);
                z = __builtin_amdgcn_mfma_f32_16x16x32_bf16(aq1, bk[kt][1], z, 0, 0, 0);
                s[kt] = z;
            }
            const bool needmask = causal && (k0 + 63 > tb);
#pragma unroll
            for (int r = 0; r < 4; ++r) {
                const int qg = tb + qd * 4 + r;
                float e[4];
#pragma unroll
                for (int kt = 0; kt < 4; ++kt) {
                    float ev = __builtin_amdgcn_exp2f(s[kt][r]);
                    if (needmask && (k0 + kt * 16 + l15 > qg)) ev = 0.f;
                    e[kt] = ev;
                }
                lpart[r] += (e[0] + e[1]) + (e[2] + e[3]);
                unsigned int lo = __builtin_amdgcn_perm(fbits(e[1]), fbits(e[0]), 0x07060302u);
                unsigned int hi = __builtin_amdgcn_perm(fbits(e[3]), fbits(e[2]), 0x07060302u);
                uint2 pk; pk.x = lo; pk.y = hi;
                const int prow = qd * 4 + r;
                *(uint2*)&Ps[wave][prow][(l15 * 4) ^ ((prow & 7) << 3)] = pk;
            }
            bf16x8 bv[4][2];
#pragma unroll
            for (int dt = 0; dt < 4; ++dt)
#pragma unroll
                for (int c = 0; c < 2; ++c)
                    bv[dt][c] = *(const bf16x8*)&Vs[dt * 16 + l15][((c * 4 + qd) ^ l7) * 8];
            bf16x8 ap0 = *(const bf16x8*)&Ps[wave][l15][(qd ^ l7) * 8];
            bf16x8 ap1 = *(const bf16x8*)&Ps[wave][l15][((4 + qd) ^ l7) * 8];
#pragma unroll
            for (int dt = 0; dt < 4; ++dt) {
                oacc[dt] = __builtin_amdgcn_mfma_f32_16x16x32_bf16(
                    ap0, bv[dt][0], oacc[dt], 0, 0, 0);
                oacc[dt] = __builtin_amdgcn_mfma_f32_16x16x32_bf16(
                    ap1, bv[dt][1], oacc[dt], 0, 0, 0);
            }
        }
    }

#pragma unroll
    for (int r = 0; r < 4; ++r) {
        float l = lpart[r];
        l += __shfl_xor(l, 1);
        l += __shfl_xor(l, 2);
        l += __shfl_xor(l, 4);
        l += __shfl_xor(l, 8);
        float inv = 1.f / l;
        long row = (long)(b * Nq + tb + qd * 4 + r);
#pragma unroll
        for (int dt = 0; dt < 4; ++dt)
            O[row * 1024 + h * 64 + dt * 16 + l15] = f2bf(oacc[dt][r] * inv);
    }
}

// --------------------------- residual + LayerNorm --------------------------
template<int ND, int RESBF>
__global__ __launch_bounds__(256) void ln_res_kernel(
    const void* __restrict__ res, const unsigned short* __restrict__ delta,
    long dstride, const float* __restrict__ g, const float* __restrict__ beta,
    float* __restrict__ yout, unsigned short* __restrict__ ybf)
{
    __shared__ float red[8];
    const int row = blockIdx.x;
    const int tid = threadIdx.x;
    const long base = (long)row * 1024 + tid * 4;
    float v0, v1, v2, v3;
    if (RESBF) {
        ushort4 a = *(const ushort4*)((const unsigned short*)res + base);
        v0 = bf2f(a.x); v1 = bf2f(a.y); v2 = bf2f(a.z); v3 = bf2f(a.w);
    } else {
        float4 a = *(const float4*)((const float*)res + base);
        v0 = a.x; v1 = a.y; v2 = a.z; v3 = a.w;
    }
#pragma unroll
    for (int t = 0; t < ND; ++t) {
        ushort4 d = *(const ushort4*)(delta + t * dstride + base);
        v0 += bf2f(d.x); v1 += bf2f(d.y); v2 += bf2f(d.z); v3 += bf2f(d.w);
    }
    float s  = v0 + v1 + v2 + v3;
    float ss = v0 * v0 + v1 * v1 + v2 * v2 + v3 * v3;
#pragma unroll
    for (int off = 1; off < 64; off <<= 1) {
        s  += __shfl_xor(s, off);
        ss += __shfl_xor(ss, off);
    }
    const int wave = tid >> 6;
    if ((tid & 63) == 0) { red[wave] = s; red[4 + wave] = ss; }
    __syncthreads();
    float st  = red[0] + red[1] + red[2] + red[3];
    float sst = red[4] + red[5] + red[6] + red[7];
    float mean = st * (1.f / 1024.f);
    float var  = sst * (1.f / 1024.f) - mean * mean;
    float inv  = rsqrtf(var + 1e-5f);
    const int c = tid * 4;
    float y0 = (v0 - mean) * inv * g[c + 0] + beta[c + 0];
    float y1 = (v1 - mean) * inv * g[c + 1] + beta[c + 1];
    float y2 = (v2 - mean) * inv * g[c + 2] + beta[c + 2];
    float y3 = (v3 - mean) * inv * g[c + 3] + beta[c + 3];
    if (yout) *(float4*)(yout + base) = make_float4(y0, y1, y2, y3);
    if (ybf) {
        ushort4 o;
        o.x = f2bf(y0); o.y = f2bf(y1); o.z = f2bf(y2); o.w = f2bf(y3);
        *(ushort4*)(ybf + base) = o;
    }
}

// --------------------------- launch ----------------------------------------
extern "C" void kernel_launch(void* const* d_in, const int* in_sizes, int n_in,
                              void* d_out, int out_size, void* d_ws, size_t ws_size,
                              hipStream_t stream)
{
    const int B = 2, N = 2048, M = 1024, D = 1024, FF = 4096;
    const int TN = B * N;   // 4096
    const int TM = B * M;   // 2048
    const size_t MB = 1024 * 1024;

    const float* x     = (const float*)d_in[0];
    const float* mem   = (const float*)d_in[1];
    const float* sa_wq = (const float*)d_in[3];  const float* sa_bq = (const float*)d_in[4];
    const float* sa_wk = (const float*)d_in[5];  const float* sa_bk = (const float*)d_in[6];
    const float* sa_wv = (const float*)d_in[7];  const float* sa_bv = (const float*)d_in[8];
    const float* sa_wo = (const float*)d_in[9];  const float* sa_bo = (const float*)d_in[10];
    const float* ca_wq = (const float*)d_in[11]; const float* ca_bq = (const float*)d_in[12];
    const float* ca_wk = (const float*)d_in[13]; const float* ca_bk = (const float*)d_in[14];
    const float* ca_wv = (const float*)d_in[15]; const float* ca_bv = (const float*)d_in[16];
    const float* ca_wo = (const float*)d_in[17]; const float* ca_bo = (const float*)d_in[18];
    const float* ff_w1 = (const float*)d_in[19]; const float* ff_b1 = (const float*)d_in[20];
    const float* ff_w2 = (const float*)d_in[21]; const float* ff_b2 = (const float*)d_in[22];
    const float* ln1_g = (const float*)d_in[23]; const float* ln1_b = (const float*)d_in[24];
    const float* ln2_g = (const float*)d_in[25]; const float* ln2_b = (const float*)d_in[26];
    const float* ln3_g = (const float*)d_in[27]; const float* ln3_b = (const float*)d_in[28];

    char* w = (char*)d_ws;
    size_t off = 0;
    auto alloc = [&](size_t bytes) -> char* {
        char* p = w + off; off += (bytes + 255) & ~(size_t)255; return p;
    };

    unsigned short* xb   = (unsigned short*)alloc((size_t)TN * D * 2);   // 8 MB
    unsigned short* memb = (unsigned short*)alloc((size_t)TM * D * 2);   // 4 MB
    unsigned short* wqkv = (unsigned short*)alloc((size_t)3 * D * D * 2);// 6 MB
    unsigned short* wos  = (unsigned short*)alloc((size_t)D * D * 2);
    unsigned short* wqc  = (unsigned short*)alloc((size_t)D * D * 2);
    unsigned short* wkvc = (unsigned short*)alloc((size_t)2 * D * D * 2);// 4 MB
    unsigned short* woc  = (unsigned short*)alloc((size_t)D * D * 2);
    unsigned short* w1b  = (unsigned short*)alloc((size_t)FF * D * 2);   // 8 MB
    unsigned short* w2b  = (unsigned short*)alloc((size_t)D * FF * 2);   // 8 MB
    // big overlapped region (80 MB), phase-disjoint liveness:
    //   phase1: qkv [0,24)  kvb [32,40)  ab [24,32)
    //   phase2: qb [40,48)  kvb [32,40)  ab [24,32)
    //   phase3: hb [0,32)
    //   tmpbf [48,56): single 8 MB bf16 delta (no split-K slices in R18)
    char* big = alloc((size_t)80 * MB);
    unsigned short* qkv   = (unsigned short*)big;
    unsigned short* ab    = (unsigned short*)(big + 24 * MB);
    unsigned short* kvb   = (unsigned short*)(big + 32 * MB);
    unsigned short* qb    = (unsigned short*)(big + 40 * MB);
    unsigned short* hb    = (unsigned short*)big;
    unsigned short* tmpbf = (unsigned short*)(big + 48 * MB);
    const long      TSL   = (long)TN * D;        // slice stride (elements)
    float* bqkv = (float*)alloc((size_t)3 * D * 4);
    float* bkvc = (float*)alloc((size_t)2 * D * 4);

    // ---- fused fp32->bf16 conversions + bias concat (one launch) ----
    ConvArgs ca;
    const float* srcs[12] = {x, mem, sa_wq, sa_wk, sa_wv, sa_wo,
                             ca_wq, ca_wk, ca_wv, ca_wo, ff_w1, ff_w2};
    unsigned short* dsts[12] = {xb, memb, wqkv, wqkv + (size_t)D * D,
                                wqkv + (size_t)2 * D * D, wos, wqc, wkvc,
                                wkvc + (size_t)D * D, woc, w1b, w2b};
    long ns[12] = {(long)TN * D, (long)TM * D, (long)D * D, (long)D * D,
                   (long)D * D, (long)D * D, (long)D * D, (long)D * D,
                   (long)D * D, (long)D * D, (long)FF * D, (long)D * FF};
    int total_blk = 0;
    for (int i = 0; i < 12; ++i) {
        ca.src[i] = srcs[i]; ca.dst[i] = dsts[i];
        ca.n4[i] = (int)(ns[i] / 4);
        ca.blk_ofs[i] = total_blk;
        total_blk += (ca.n4[i] + 255) / 256;
    }
    ca.blk_ofs[12] = total_blk;
    ca.bq = sa_bq; ca.bk = sa_bk; ca.bv = sa_bv; ca.ck = ca_bk; ca.cv = ca_bv;
    ca.bqkv = bqkv; ca.bkvc = bkvc;
    conv_multi<<<dim3(total_blk + 20), dim3(256), 0, stream>>>(ca);

    dim3 blk(256);
    dim3 blk8(512);
    const unsigned int LDS8 = 131072;   // 128 KiB dynamic LDS

    // ---- projections: selfQKV + crossKV, 256^2 2-barrier, XCD regions -----
    gemm8_dual<<<dim3(256), blk8, LDS8, stream>>>(
        xb,   wqkv, bqkv, qkv, D, 3 * D,
        memb, wkvc, bkvc, kvb, D, 2 * D);

    // ---- self-attention ----
    attn_kernel<<<dim3(N / 64, 16, B), blk, 0, stream>>>(
        qkv, 3 * D, qkv, 3 * D, D, 2 * D, ab, N, N, 1);
    gemm_bt<128, 128, 0, 1><<<dim3(D / 128, TN / 128), blk, 0, stream>>>(
        ab, wos, sa_bo, tmpbf, D, D, 0);
    ln_res_kernel<1, 0><<<dim3(TN), blk, 0, stream>>>(
        x, tmpbf, TSL, ln1_g, ln1_b, nullptr, xb);

    // ---- cross-attention ----
    gemm_bt<128, 128, 0, 1><<<dim3(D / 128, TN / 128), blk, 0, stream>>>(
        xb, wqc, ca_bq, qb, D, D, 0);
    attn_kernel<<<dim3(N / 64, 16, B), blk, 0, stream>>>(
        qb, D, kvb, 2 * D, 0, D, ab, N, M, 0);
    gemm_bt<128, 128, 0, 1><<<dim3(D / 128, TN / 128), blk, 0, stream>>>(
        ab, woc, ca_bo, tmpbf, D, D, 0);
    ln_res_kernel<1, 1><<<dim3(TN), blk, 0, stream>>>(
        xb, tmpbf, TSL, ln2_g, ln2_b, nullptr, xb);

    // ---- FFN ----
    gemm8_bt<1, 1, 1><<<dim3(256), blk8, LDS8, stream>>>(
        xb, w1b, ff_b1, hb, D, FF, 0);
    gemm_bt<128, 128, 0, 1><<<dim3(D / 128, TN / 128), blk, 0, stream>>>(
        hb, w2b, ff_b2, tmpbf, FF, D, 0);
    ln_res_kernel<1, 1><<<dim3(TN), blk, 0, stream>>>(
        xb, tmpbf, TSL, ln3_g, ln3_b, (float*)d_out, nullptr);
}

// Round 7
// 464.437 us; speedup vs baseline: 1.0652x; 1.0652x over previous
//
#include <hip/hip_runtime.h>

// ---------------------------------------------------------------------------
// DecoderBlock: x = LN1(x + SelfAttn(x));  x = LN2(x + CrossAttn(x, mem));
//               x = LN3(x + W2·relu(W1·x + b1) + b2)
// B=2, N=2048, M=1024, D=1024, H=16, Dh=64, FF=4096.
// R19 = R16 structure restored (R18's 128^2 grids were 1 block/CU = 4
//   waves -> 79.5us; occupancy ladder measured: 4w=79.5, 8w(gemm8)=47,
//   24w(128x64)=51 -> gemm8 stays for big GEMMs, 128x64 SK for small)
//   + R17 attn keepers (Q-prescale, v_perm packing)
//   + ONE change: attn q-tile 64 -> 128 (8 waves/512thr; waves 0-3 stage V,
//     4-7 stage K). Halves per-query staging VALU + K/V refetch
//     (attn was co-top 48.8us x2, VALUBusy 47%, MfmaUtil 13.5%).
// ---------------------------------------------------------------------------

typedef __attribute__((ext_vector_type(8))) short bf16x8;   // 8 bf16 (4 VGPRs)
typedef __attribute__((ext_vector_type(4))) float f32x4;

__device__ __forceinline__ unsigned short f2bf(float f) {
    union { float f; unsigned int u; } v; v.f = f;
    unsigned int r = v.u + 0x7fffu + ((v.u >> 16) & 1u);   // RNE
    return (unsigned short)(r >> 16);
}
__device__ __forceinline__ float bf2f(unsigned short u) {
    union { unsigned int u; float f; } v; v.u = (unsigned int)u << 16;
    return v.f;
}
__device__ __forceinline__ unsigned int fbits(float f) {
    union { float f; unsigned int u; } v; v.f = f;
    return v.u;
}

// ------------------- fused fp32->bf16 conversion + bias concat -------------
struct ConvArgs {
    const float* src[12];
    unsigned short* dst[12];
    int blk_ofs[13];
    int n4[12];
    const float* bq; const float* bk; const float* bv;
    const float* ck; const float* cv;
    float* bqkv; float* bkvc;
};
__global__ __launch_bounds__(256) void conv_multi(ConvArgs a)
{
    int bid = blockIdx.x;
    if (bid >= a.blk_ofs[12]) {                  // bias-concat tail
        int i = (bid - a.blk_ofs[12]) * 256 + threadIdx.x;   // 0..5119
        if (i < 1024)       a.bqkv[i] = a.bq[i];
        else if (i < 2048)  a.bqkv[i] = a.bk[i - 1024];
        else if (i < 3072)  a.bqkv[i] = a.bv[i - 2048];
        else if (i < 4096)  a.bkvc[i - 3072] = a.ck[i - 3072];
        else if (i < 5120)  a.bkvc[i - 3072] = a.cv[i - 4096];
        return;
    }
    int s = 0;
#pragma unroll
    for (int t = 0; t < 12; ++t) if (bid >= a.blk_ofs[t + 1]) s = t + 1;
    int i = (bid - a.blk_ofs[s]) * 256 + threadIdx.x;
    if (i >= a.n4[s]) return;
    float4 v = ((const float4*)a.src[s])[i];
    ushort4 o;
    o.x = f2bf(v.x); o.y = f2bf(v.y); o.z = f2bf(v.z); o.w = f2bf(v.w);
    ((ushort4*)a.dst[s])[i] = o;
}

// --------------------------- bf16 GEMM core (128x64, 2-phase) --------------
// Small-GEMM path: selfO/crossO (SK=2), crossQ (SK=1). 24KB LDS.
template<int TM, int TN, int EPI, int SK>
__device__ __forceinline__ void gemm_body(
    unsigned short (*As)[64], unsigned short (*Bs)[64],
    const unsigned short* __restrict__ A, const unsigned short* __restrict__ W,
    const float* __restrict__ bias, unsigned short* __restrict__ out,
    int K, int Ncols, long slice_stride, int bid, int gx, int zslice)
{
    constexpr int AI = TM / 32;
    constexpr int BJ = TN / 32;

    const int tid  = threadIdx.x;
    const int lane = tid & 63;
    const int wave = tid >> 6;
    const int qd   = lane >> 4;
    const int l15  = lane & 15;
    const int wm   = (wave >> 1) * (TM / 2);
    const int wn   = (wave & 1) * (TN / 2);

    const int gpg = 8 * gx;                       // GROUP_M=8 swizzle
    const long m0 = (long)((bid / gpg) * 8 + (bid & 7)) * TM;
    const long n0 = (long)((bid % gpg) >> 3) * TN;

    f32x4 acc[AI][BJ] = {};

    const int srow = lane >> 3;
    const int scol = (((lane & 7) ^ srow)) * 8;   // XOR-swizzled group
    const unsigned short* Ag = A + (m0 + wave * (8 * AI) + srow) * (long)K + scol;
    const unsigned short* Wg = W + (n0 + wave * (8 * BJ) + srow) * (long)K + scol;

    const int ksl   = K / SK;
    const int kbase = (SK > 1) ? zslice * ksl : 0;

    for (int k0 = kbase; k0 < kbase + ksl; k0 += 64) {
#pragma unroll
        for (int c = 0; c < AI; ++c)
            __builtin_amdgcn_global_load_lds(
                (const __attribute__((address_space(1))) unsigned int*)(Ag + (long)c * 8 * K + k0),
                (__attribute__((address_space(3))) unsigned int*)((char*)&As[0][0] + (wave * AI + c) * 1024),
                16, 0, 0);
#pragma unroll
        for (int c = 0; c < BJ; ++c)
            __builtin_amdgcn_global_load_lds(
                (const __attribute__((address_space(1))) unsigned int*)(Wg + (long)c * 8 * K + k0),
                (__attribute__((address_space(3))) unsigned int*)((char*)&Bs[0][0] + (wave * BJ + c) * 1024),
                16, 0, 0);
        __syncthreads();
#pragma unroll
        for (int kk = 0; kk < 64; kk += 32) {
            const int pg = ((((kk >> 3) + qd)) ^ (l15 & 7)) * 8;  // de-swizzle
            bf16x8 af[AI], bw[BJ];
#pragma unroll
            for (int i = 0; i < AI; ++i)
                af[i] = *(const bf16x8*)&As[wm + i * 16 + l15][pg];
#pragma unroll
            for (int j = 0; j < BJ; ++j)
                bw[j] = *(const bf16x8*)&Bs[wn + j * 16 + l15][pg];
#pragma unroll
            for (int i = 0; i < AI; ++i)
#pragma unroll
                for (int j = 0; j < BJ; ++j)
                    acc[i][j] = __builtin_amdgcn_mfma_f32_16x16x32_bf16(
                        af[i], bw[j], acc[i][j], 0, 0, 0);
        }
        __syncthreads();
    }

    // epilogue. C/D layout: col = lane&15, row = quad*4 + reg  [m89-verified]
    unsigned short* op = out + ((SK > 1) ? (long)zslice * slice_stride : 0);
#pragma unroll
    for (int j = 0; j < BJ; ++j) {
        long col = n0 + wn + j * 16 + l15;
        float bv = (SK == 1 || zslice == 0) ? bias[col] : 0.f;
#pragma unroll
        for (int i = 0; i < AI; ++i) {
#pragma unroll
            for (int r = 0; r < 4; ++r) {
                long row = m0 + wm + i * 16 + qd * 4 + r;
                float v = acc[i][j][r] + bv;
                if (EPI == 1) v = (v > 0.f) ? v : 0.f;
                op[row * Ncols + col] = f2bf(v);
            }
        }
    }
}

template<int TM, int TN, int EPI, int SK>
__global__ __launch_bounds__(256) void gemm_bt(
    const unsigned short* __restrict__ A, const unsigned short* __restrict__ W,
    const float* __restrict__ bias, unsigned short* __restrict__ out,
    int K, int Ncols, long slice_stride)
{
    __shared__ unsigned short As[TM][64];
    __shared__ unsigned short Bs[TN][64];
    const int bid = blockIdx.y * gridDim.x + blockIdx.x;
    gemm_body<TM, TN, EPI, SK>(As, Bs, A, W, bias, out, K, Ncols, slice_stride,
                               bid, gridDim.x, (int)blockIdx.z);
}

// --------------------------- 256^2 2-barrier GEMM --------------------------
// BM=BN=256, BK=64, 512 thr (8 waves, 2M x 4N). LDS 128 KiB double-buffered;
// XOR-swizzle staging source + reads; per K-group: {pre-stage A(g+1)-tails |
// reads+MFMA i-low | MID bar | stage g+2 into dead slots | reads+MFMA i-high
// (B in regs) | vmcnt(6) + END bar}.
template<int EPI, int SK>
__device__ __forceinline__ void gemm8_body(
    unsigned short* Ab, unsigned short* Bb,
    const unsigned short* __restrict__ A, const unsigned short* __restrict__ W,
    const float* __restrict__ bias, unsigned short* __restrict__ out,
    int K, int Ncols, long slice_stride, int mb, int nb, int zslice)
{
    const int tid  = threadIdx.x;       // 0..511
    const int lane = tid & 63;
    const int wave = tid >> 6;          // 0..7
    const int qd   = lane >> 4;
    const int l15  = lane & 15;
    const int wm   = (wave >> 2) * 128; // 2 M-waves
    const int wn   = (wave & 3) * 64;   // 4 N-waves

    const long m0 = (long)mb * 256;
    const long n0 = (long)nb * 256;

    const int ksl   = K / SK;
    const int kbase = (SK > 1) ? zslice * ksl : 0;
    const int NG    = ksl / 64;         // 16 for all call sites here

    f32x4 acc[8][4] = {};

    const int srow = tid >> 3;                       // 0..63
    const int sgrp = ((tid & 7) ^ (srow & 7)) * 8;
    const unsigned short* Ag = A + (m0 + srow) * (long)K + kbase + sgrp;
    const unsigned short* Wg = W + (n0 + srow) * (long)K + kbase + sgrp;

    auto stA = [&](int db, int r0, int kt) {
        __builtin_amdgcn_global_load_lds(
            (const __attribute__((address_space(1))) unsigned int*)(Ag + (long)r0 * K + kt * 64),
            (__attribute__((address_space(3))) unsigned int*)(Ab + db * 16384 + r0 * 64 + wave * 512),
            16, 0, 0);
    };
    auto stB = [&](int db, int r0, int kt) {
        __builtin_amdgcn_global_load_lds(
            (const __attribute__((address_space(1))) unsigned int*)(Wg + (long)r0 * K + kt * 64),
            (__attribute__((address_space(3))) unsigned int*)(Bb + db * 16384 + r0 * 64 + wave * 512),
            16, 0, 0);
    };
    auto rdA = [&](int db, int row, int kk) -> bf16x8 {
        const int p = (((kk << 2) + qd) ^ (l15 & 7)) << 3;
        return *(const bf16x8*)(Ab + db * 16384 + row * 64 + p);
    };
    auto rdB = [&](int db, int row, int kk) -> bf16x8 {
        const int p = (((kk << 2) + qd) ^ (l15 & 7)) << 3;
        return *(const bf16x8*)(Bb + db * 16384 + row * 64 + p);
    };

    // ---- prologue: tile0 full (8) -> buf0; tile1 B + A-heads (6) -> buf1 --
#pragma unroll
    for (int h = 0; h < 4; ++h) stA(0, h * 64, 0);
#pragma unroll
    for (int h = 0; h < 4; ++h) stB(0, h * 64, 0);
    if (NG > 1) {
#pragma unroll
        for (int h = 0; h < 4; ++h) stB(1, h * 64, 1);
        stA(1, 0, 1); stA(1, 128, 1);
        asm volatile("s_waitcnt vmcnt(6)" ::: "memory");   // tile0 resident
    } else {
        asm volatile("s_waitcnt vmcnt(0)" ::: "memory");
    }
    __builtin_amdgcn_s_barrier();

    for (int g = 0; g < NG; ++g) {
        const int db = g & 1, ob = db ^ 1;
        bf16x8 af[4][2], bw[4][2];

        if (g + 1 < NG) { stA(ob, 64, g + 1); stA(ob, 192, g + 1); }

        // ---- h1: i-low half ----
#pragma unroll
        for (int i = 0; i < 4; ++i)
#pragma unroll
            for (int kk = 0; kk < 2; ++kk)
                af[i][kk] = rdA(db, wm + i * 16 + l15, kk);
#pragma unroll
        for (int j = 0; j < 4; ++j)
#pragma unroll
            for (int kk = 0; kk < 2; ++kk)
                bw[j][kk] = rdB(db, wn + j * 16 + l15, kk);
        __builtin_amdgcn_s_setprio(1);
#pragma unroll
        for (int i = 0; i < 4; ++i)
#pragma unroll
            for (int j = 0; j < 4; ++j) {
                acc[i][j] = __builtin_amdgcn_mfma_f32_16x16x32_bf16(af[i][0], bw[j][0], acc[i][j], 0, 0, 0);
                acc[i][j] = __builtin_amdgcn_mfma_f32_16x16x32_bf16(af[i][1], bw[j][1], acc[i][j], 0, 0, 0);
            }
        __builtin_amdgcn_s_setprio(0);
        __builtin_amdgcn_s_barrier();                      // MID

        if (g + 2 < NG) {
#pragma unroll
            for (int h = 0; h < 4; ++h) stB(db, h * 64, g + 2);
            stA(db, 0, g + 2); stA(db, 128, g + 2);
        }

        // ---- h2: i-high half (bw in regs) ----
#pragma unroll
        for (int i = 0; i < 4; ++i)
#pragma unroll
            for (int kk = 0; kk < 2; ++kk)
                af[i][kk] = rdA(db, wm + 64 + i * 16 + l15, kk);
        __builtin_amdgcn_s_setprio(1);
#pragma unroll
        for (int i = 0; i < 4; ++i)
#pragma unroll
            for (int j = 0; j < 4; ++j) {
                acc[4 + i][j] = __builtin_amdgcn_mfma_f32_16x16x32_bf16(af[i][0], bw[j][0], acc[4 + i][j], 0, 0, 0);
                acc[4 + i][j] = __builtin_amdgcn_mfma_f32_16x16x32_bf16(af[i][1], bw[j][1], acc[4 + i][j], 0, 0, 0);
            }
        __builtin_amdgcn_s_setprio(0);

        if (g + 2 < NG)      { asm volatile("s_waitcnt vmcnt(6)" ::: "memory"); }
        else if (g + 1 < NG) { asm volatile("s_waitcnt vmcnt(0)" ::: "memory"); }
        __builtin_amdgcn_s_barrier();
    }

    // ---- epilogue. C/D layout: col = lane&15, row = quad*4 + reg ----
    unsigned short* op = out + ((SK > 1) ? (long)zslice * slice_stride : 0);
#pragma unroll
    for (int j = 0; j < 4; ++j) {
        long col = n0 + wn + j * 16 + l15;
        float bv = (SK == 1 || zslice == 0) ? bias[col] : 0.f;
#pragma unroll
        for (int i = 0; i < 8; ++i) {
#pragma unroll
            for (int r = 0; r < 4; ++r) {
                long row = m0 + wm + (i >> 2) * 64 + (i & 3) * 16 + qd * 4 + r;
                float v = acc[i][j][r] + bv;
                if (EPI == 1) v = (v > 0.f) ? v : 0.f;
                op[row * Ncols + col] = f2bf(v);
            }
        }
    }
}

// MODE 1: FFN1 16m x 16n, per-XCD region 4m x 8n.
// MODE 2: FFN2 16m x 4n x 4z, z = xcd>>1, per-XCD-pair region 8m x 4n.
template<int EPI, int SK, int MODE>
__global__ __launch_bounds__(512) void gemm8_bt(
    const unsigned short* __restrict__ A, const unsigned short* __restrict__ W,
    const float* __restrict__ bias, unsigned short* __restrict__ out,
    int K, int Ncols, long slice_stride)
{
    extern __shared__ unsigned short smem[];
    const int bid = blockIdx.x;
    const int x = bid & 7;              // assumed hw XCD (round-robin)
    const int s = bid >> 3;             // 0..31
    int mb, nb, z = 0;
    if (MODE == 1) {
        mb = (x >> 1) * 4 + (s & 3);
        nb = (x & 1) * 8 + (s >> 2);
    } else {
        z  = x >> 1;
        mb = (x & 1) * 8 + (s & 7);
        nb = s >> 3;
    }
    gemm8_body<EPI, SK>(smem, smem + 32768, A, W, bias, out, K, Ncols,
                        slice_stride, mb, nb, z);
}

// selfQKV (192 blk, region 4m x 6n) + crossKV (64 blk, region 2m x 4n).
__global__ __launch_bounds__(512) void gemm8_dual(
    const unsigned short* A0, const unsigned short* W0, const float* b0,
    unsigned short* o0, int K0, int N0,
    const unsigned short* A1, const unsigned short* W1, const float* b1,
    unsigned short* o1, int K1, int N1)
{
    extern __shared__ unsigned short smem[];
    const int bid = blockIdx.x;
    const int x = bid & 7;
    const int s = bid >> 3;             // 0..31
    if (s < 24) {
        const int mb = (x >> 1) * 4 + (s & 3);
        const int nb = (x & 1) * 6 + (s >> 2);
        gemm8_body<0, 1>(smem, smem + 32768, A0, W0, b0, o0, K0, N0, 0, mb, nb, 0);
    } else {
        const int t = s - 24;           // 0..7
        const int mb = (x >> 1) * 2 + (t & 1);
        const int nb = (x & 1) * 4 + (t >> 1);
        gemm8_body<0, 1>(smem, smem + 32768, A1, W1, b1, o1, K1, N1, 0, mb, nb, 0);
    }
}

// --------------------------- flash attention (MFMA, 8-wave, 128q) ----------
// R19: q-tile 128 (8 waves); waves 0-3 stage V, waves 4-7 stage K. Halves
// per-query staging work + K/V refetch. Ks/Vs/Ps XOR-swizzled (0 conflicts),
// Q pre-scaled by SCL (exp2 direct), v_perm packing (R17 keepers).
__global__ __launch_bounds__(512) void attn_kernel(
    const unsigned short* __restrict__ Qb, int q_stride,
    const unsigned short* __restrict__ KVb, int kv_stride, int koff, int voff,
    unsigned short* __restrict__ O,
    int Nq, int Mk, int causal)
{
    __shared__ unsigned short Ks[64][64];
    __shared__ unsigned short Vs[64][64];
    __shared__ unsigned short Ps[8][16][64];

    const int tid  = threadIdx.x;       // 0..511
    const int lane = tid & 63;
    const int wave = tid >> 6;          // 0..7
    const int qd   = lane >> 4;
    const int l15  = lane & 15;
    const int l7   = l15 & 7;
    const int h    = blockIdx.y;
    const int b    = blockIdx.z;
    int jq = blockIdx.x;
    if (causal && (b & 1)) jq = gridDim.x - 1 - jq;
    const int q0 = jq * 128;
    const int tb = q0 + wave * 16;

    const float SCL = 0.125f * 1.44269504f;

    bf16x8 aq0, aq1;
    {
        const unsigned short* qp =
            Qb + (long)(b * Nq + tb + l15) * q_stride + h * 64 + qd * 8;
        aq0 = *(const bf16x8*)qp;
        aq1 = *(const bf16x8*)(qp + 32);
#pragma unroll
        for (int j = 0; j < 8; ++j) {
            aq0[j] = (short)f2bf(bf2f((unsigned short)aq0[j]) * SCL);
            aq1[j] = (short)f2bf(bf2f((unsigned short)aq1[j]) * SCL);
        }
    }

    float lpart[4] = {};
    f32x4 oacc[4] = {};

    // staging roles: tid<256 -> V, tid>=256 -> K
    const bool vrole = (tid < 256);
    const int vt   = tid & 255;
    const int vj   = vt & 31;
    const int va_k = (vj & 15) + ((vj & 16) << 1);
    const int vfg  = (vt >> 5) * 8;                      // 0..56
    const int vpc  = (va_k & 15) * 4 + (va_k >> 4);      // even => u32-aligned
    const int krow  = vt >> 3;                           // 0..31
    const int kcol  = (vt & 7) * 8;
    const int kcolS = (((vt & 7) ^ (krow & 7))) * 8;     // (krow+32)&7 == krow&7

    const unsigned short* Kg = KVb + (long)b * Mk * kv_stride + koff + h * 64;
    const unsigned short* Vg = KVb + (long)b * Mk * kv_stride + voff + h * 64;

    bf16x8 r0, r1;   // vrole: vra/vrb; krole: kr0/kr1
    auto prefetch = [&](int k0) {
        if (vrole) {
            const unsigned short* v0 = Vg + (long)(k0 + va_k) * kv_stride + vfg;
            r0 = *(const bf16x8*)v0;
            r1 = *(const bf16x8*)(v0 + 16 * kv_stride);
        } else {
            r0 = *(const bf16x8*)(Kg + (long)(k0 + krow) * kv_stride + kcol);
            r1 = *(const bf16x8*)(Kg + (long)(k0 + krow + 32) * kv_stride + kcol);
        }
    };

    const int nk = causal ? (q0 + 128) : Mk;
    prefetch(0);

    for (int k0 = 0; k0 < nk; k0 += 64) {
        __syncthreads();
        if (vrole) {
            const unsigned int* pa = (const unsigned int*)&r0;
            const unsigned int* pb = (const unsigned int*)&r1;
#pragma unroll
            for (int w2 = 0; w2 < 4; ++w2) {
                unsigned int d0 = __builtin_amdgcn_perm(pb[w2], pa[w2], 0x05040100u);
                unsigned int d1 = __builtin_amdgcn_perm(pb[w2], pa[w2], 0x07060302u);
                const int rr0 = vfg + 2 * w2, rr1 = rr0 + 1;
                *(unsigned int*)&Vs[rr0][vpc ^ ((rr0 & 7) << 3)] = d0;
                *(unsigned int*)&Vs[rr1][vpc ^ ((rr1 & 7) << 3)] = d1;
            }
        } else {
            *(bf16x8*)&Ks[krow][kcolS]      = r0;
            *(bf16x8*)&Ks[krow + 32][kcolS] = r1;
        }
        if (k0 + 64 < nk) prefetch(k0 + 64);
        __syncthreads();

        if (!causal || (k0 <= tb + 15)) {
            bf16x8 bk[4][2];
#pragma unroll
            for (int kt = 0; kt < 4; ++kt)
#pragma unroll
                for (int c = 0; c < 2; ++c)
                    bk[kt][c] = *(const bf16x8*)&Ks[kt * 16 + l15][((c * 4 + qd) ^ l7) * 8];
            f32x4 s[4];
#pragma unroll
            for (int kt = 0; kt < 4; ++kt) {
                f32x4 z = {};
                z = __builtin_amdgcn_mfma_f32_16x16x32_bf16(aq0, bk[kt][0], z, 0, 0, 0);
                z = __builtin_amdgcn_mfma_f32_16x16x32_bf16(aq1, bk[kt][1], z, 0, 0, 0);
                s[kt] = z;
            }
            const bool needmask = causal && (k0 + 63 > tb);
#pragma unroll
            for (int r = 0; r < 4; ++r) {
                const int qg = tb + qd * 4 + r;
                float e[4];
#pragma unroll
                for (int kt = 0; kt < 4; ++kt) {
                    float ev = __builtin_amdgcn_exp2f(s[kt][r]);
                    if (needmask && (k0 + kt * 16 + l15 > qg)) ev = 0.f;
                    e[kt] = ev;
                }
                lpart[r] += (e[0] + e[1]) + (e[2] + e[3]);
                unsigned int lo = __builtin_amdgcn_perm(fbits(e[1]), fbits(e[0]), 0x07060302u);
                unsigned int hi = __builtin_amdgcn_perm(fbits(e[3]), fbits(e[2]), 0x07060302u);
                uint2 pk; pk.x = lo; pk.y = hi;
                const int prow = qd * 4 + r;
                *(uint2*)&Ps[wave][prow][(l15 * 4) ^ ((prow & 7) << 3)] = pk;
            }
            bf16x8 bv[4][2];
#pragma unroll
            for (int dt = 0; dt < 4; ++dt)
#pragma unroll
                for (int c = 0; c < 2; ++c)
                    bv[dt][c] = *(const bf16x8*)&Vs[dt * 16 + l15][((c * 4 + qd) ^ l7) * 8];
            bf16x8 ap0 = *(const bf16x8*)&Ps[wave][l15][(qd ^ l7) * 8];
            bf16x8 ap1 = *(const bf16x8*)&Ps[wave][l15][((4 + qd) ^ l7) * 8];
#pragma unroll
            for (int dt = 0; dt < 4; ++dt) {
                oacc[dt] = __builtin_amdgcn_mfma_f32_16x16x32_bf16(
                    ap0, bv[dt][0], oacc[dt], 0, 0, 0);
                oacc[dt] = __builtin_amdgcn_mfma_f32_16x16x32_bf16(
                    ap1, bv[dt][1], oacc[dt], 0, 0, 0);
            }
        }
    }

#pragma unroll
    for (int r = 0; r < 4; ++r) {
        float l = lpart[r];
        l += __shfl_xor(l, 1);
        l += __shfl_xor(l, 2);
        l += __shfl_xor(l, 4);
        l += __shfl_xor(l, 8);
        float inv = 1.f / l;
        long row = (long)(b * Nq + tb + qd * 4 + r);
#pragma unroll
        for (int dt = 0; dt < 4; ++dt)
            O[row * 1024 + h * 64 + dt * 16 + l15] = f2bf(oacc[dt][r] * inv);
    }
}

// --------------------------- residual + LayerNorm --------------------------
template<int ND, int RESBF>
__global__ __launch_bounds__(256) void ln_res_kernel(
    const void* __restrict__ res, const unsigned short* __restrict__ delta,
    long dstride, const float* __restrict__ g, const float* __restrict__ beta,
    float* __restrict__ yout, unsigned short* __restrict__ ybf)
{
    __shared__ float red[8];
    const int row = blockIdx.x;
    const int tid = threadIdx.x;
    const long base = (long)row * 1024 + tid * 4;
    float v0, v1, v2, v3;
    if (RESBF) {
        ushort4 a = *(const ushort4*)((const unsigned short*)res + base);
        v0 = bf2f(a.x); v1 = bf2f(a.y); v2 = bf2f(a.z); v3 = bf2f(a.w);
    } else {
        float4 a = *(const float4*)((const float*)res + base);
        v0 = a.x; v1 = a.y; v2 = a.z; v3 = a.w;
    }
#pragma unroll
    for (int t = 0; t < ND; ++t) {
        ushort4 d = *(const ushort4*)(delta + t * dstride + base);
        v0 += bf2f(d.x); v1 += bf2f(d.y); v2 += bf2f(d.z); v3 += bf2f(d.w);
    }
    float s  = v0 + v1 + v2 + v3;
    float ss = v0 * v0 + v1 * v1 + v2 * v2 + v3 * v3;
#pragma unroll
    for (int off = 1; off < 64; off <<= 1) {
        s  += __shfl_xor(s, off);
        ss += __shfl_xor(ss, off);
    }
    const int wave = tid >> 6;
    if ((tid & 63) == 0) { red[wave] = s; red[4 + wave] = ss; }
    __syncthreads();
    float st  = red[0] + red[1] + red[2] + red[3];
    float sst = red[4] + red[5] + red[6] + red[7];
    float mean = st * (1.f / 1024.f);
    float var  = sst * (1.f / 1024.f) - mean * mean;
    float inv  = rsqrtf(var + 1e-5f);
    const int c = tid * 4;
    float y0 = (v0 - mean) * inv * g[c + 0] + beta[c + 0];
    float y1 = (v1 - mean) * inv * g[c + 1] + beta[c + 1];
    float y2 = (v2 - mean) * inv * g[c + 2] + beta[c + 2];
    float y3 = (v3 - mean) * inv * g[c + 3] + beta[c + 3];
    if (yout) *(float4*)(yout + base) = make_float4(y0, y1, y2, y3);
    if (ybf) {
        ushort4 o;
        o.x = f2bf(y0); o.y = f2bf(y1); o.z = f2bf(y2); o.w = f2bf(y3);
        *(ushort4*)(ybf + base) = o;
    }
}

// --------------------------- launch ----------------------------------------
extern "C" void kernel_launch(void* const* d_in, const int* in_sizes, int n_in,
                              void* d_out, int out_size, void* d_ws, size_t ws_size,
                              hipStream_t stream)
{
    const int B = 2, N = 2048, M = 1024, D = 1024, FF = 4096;
    const int TN = B * N;   // 4096
    const int TM = B * M;   // 2048
    const size_t MB = 1024 * 1024;

    const float* x     = (const float*)d_in[0];
    const float* mem   = (const float*)d_in[1];
    const float* sa_wq = (const float*)d_in[3];  const float* sa_bq = (const float*)d_in[4];
    const float* sa_wk = (const float*)d_in[5];  const float* sa_bk = (const float*)d_in[6];
    const float* sa_wv = (const float*)d_in[7];  const float* sa_bv = (const float*)d_in[8];
    const float* sa_wo = (const float*)d_in[9];  const float* sa_bo = (const float*)d_in[10];
    const float* ca_wq = (const float*)d_in[11]; const float* ca_bq = (const float*)d_in[12];
    const float* ca_wk = (const float*)d_in[13]; const float* ca_bk = (const float*)d_in[14];
    const float* ca_wv = (const float*)d_in[15]; const float* ca_bv = (const float*)d_in[16];
    const float* ca_wo = (const float*)d_in[17]; const float* ca_bo = (const float*)d_in[18];
    const float* ff_w1 = (const float*)d_in[19]; const float* ff_b1 = (const float*)d_in[20];
    const float* ff_w2 = (const float*)d_in[21]; const float* ff_b2 = (const float*)d_in[22];
    const float* ln1_g = (const float*)d_in[23]; const float* ln1_b = (const float*)d_in[24];
    const float* ln2_g = (const float*)d_in[25]; const float* ln2_b = (const float*)d_in[26];
    const float* ln3_g = (const float*)d_in[27]; const float* ln3_b = (const float*)d_in[28];

    char* w = (char*)d_ws;
    size_t off = 0;
    auto alloc = [&](size_t bytes) -> char* {
        char* p = w + off; off += (bytes + 255) & ~(size_t)255; return p;
    };

    unsigned short* xb   = (unsigned short*)alloc((size_t)TN * D * 2);   // 8 MB
    unsigned short* memb = (unsigned short*)alloc((size_t)TM * D * 2);   // 4 MB
    unsigned short* wqkv = (unsigned short*)alloc((size_t)3 * D * D * 2);// 6 MB
    unsigned short* wos  = (unsigned short*)alloc((size_t)D * D * 2);
    unsigned short* wqc  = (unsigned short*)alloc((size_t)D * D * 2);
    unsigned short* wkvc = (unsigned short*)alloc((size_t)2 * D * D * 2);// 4 MB
    unsigned short* woc  = (unsigned short*)alloc((size_t)D * D * 2);
    unsigned short* w1b  = (unsigned short*)alloc((size_t)FF * D * 2);   // 8 MB
    unsigned short* w2b  = (unsigned short*)alloc((size_t)D * FF * 2);   // 8 MB
    // big overlapped region (80 MB), phase-disjoint liveness (R10 layout):
    //   phase1: qkv [0,24)  kvb [32,40)  ab [24,32)
    //   phase2: qb [40,48)  kvb [32,40)  ab [24,32)
    //   phase3: hb [0,32)
    //   partials: tmpbf [48,80) (up to 4 x 8 MB bf16 slices)
    char* big = alloc((size_t)80 * MB);
    unsigned short* qkv   = (unsigned short*)big;
    unsigned short* ab    = (unsigned short*)(big + 24 * MB);
    unsigned short* kvb   = (unsigned short*)(big + 32 * MB);
    unsigned short* qb    = (unsigned short*)(big + 40 * MB);
    unsigned short* hb    = (unsigned short*)big;
    unsigned short* tmpbf = (unsigned short*)(big + 48 * MB);
    const long      TSL   = (long)TN * D;        // slice stride (elements)
    float* bqkv = (float*)alloc((size_t)3 * D * 4);
    float* bkvc = (float*)alloc((size_t)2 * D * 4);

    // ---- fused fp32->bf16 conversions + bias concat (one launch) ----
    ConvArgs ca;
    const float* srcs[12] = {x, mem, sa_wq, sa_wk, sa_wv, sa_wo,
                             ca_wq, ca_wk, ca_wv, ca_wo, ff_w1, ff_w2};
    unsigned short* dsts[12] = {xb, memb, wqkv, wqkv + (size_t)D * D,
                                wqkv + (size_t)2 * D * D, wos, wqc, wkvc,
                                wkvc + (size_t)D * D, woc, w1b, w2b};
    long ns[12] = {(long)TN * D, (long)TM * D, (long)D * D, (long)D * D,
                   (long)D * D, (long)D * D, (long)D * D, (long)D * D,
                   (long)D * D, (long)D * D, (long)FF * D, (long)D * FF};
    int total_blk = 0;
    for (int i = 0; i < 12; ++i) {
        ca.src[i] = srcs[i]; ca.dst[i] = dsts[i];
        ca.n4[i] = (int)(ns[i] / 4);
        ca.blk_ofs[i] = total_blk;
        total_blk += (ca.n4[i] + 255) / 256;
    }
    ca.blk_ofs[12] = total_blk;
    ca.bq = sa_bq; ca.bk = sa_bk; ca.bv = sa_bv; ca.ck = ca_bk; ca.cv = ca_bv;
    ca.bqkv = bqkv; ca.bkvc = bkvc;
    conv_multi<<<dim3(total_blk + 20), dim3(256), 0, stream>>>(ca);

    dim3 blk(256);
    dim3 blk8(512);
    const unsigned int LDS8 = 131072;   // 128 KiB dynamic LDS

    // ---- projections: selfQKV + crossKV, 256^2 2-barrier, XCD regions -----
    gemm8_dual<<<dim3(256), blk8, LDS8, stream>>>(
        xb,   wqkv, bqkv, qkv, D, 3 * D,
        memb, wkvc, bkvc, kvb, D, 2 * D);

    // ---- self-attention ----
    attn_kernel<<<dim3(N / 128, 16, B), blk8, 0, stream>>>(
        qkv, 3 * D, qkv, 3 * D, D, 2 * D, ab, N, N, 1);
    gemm_bt<128, 64, 0, 2><<<dim3(D / 64, TN / 128, 2), blk, 0, stream>>>(
        ab, wos, sa_bo, tmpbf, D, D, TSL);
    ln_res_kernel<2, 0><<<dim3(TN), blk, 0, stream>>>(
        x, tmpbf, TSL, ln1_g, ln1_b, nullptr, xb);

    // ---- cross-attention ----
    gemm_bt<128, 64, 0, 1><<<dim3(D / 64, TN / 128), blk, 0, stream>>>(
        xb, wqc, ca_bq, qb, D, D, 0);
    attn_kernel<<<dim3(N / 128, 16, B), blk8, 0, stream>>>(
        qb, D, kvb, 2 * D, 0, D, ab, N, M, 0);
    gemm_bt<128, 64, 0, 2><<<dim3(D / 64, TN / 128, 2), blk, 0, stream>>>(
        ab, woc, ca_bo, tmpbf, D, D, TSL);
    ln_res_kernel<2, 1><<<dim3(TN), blk, 0, stream>>>(
        xb, tmpbf, TSL, ln2_g, ln2_b, nullptr, xb);

    // ---- FFN ----
    gemm8_bt<1, 1, 1><<<dim3(256), blk8, LDS8, stream>>>(
        xb, w1b, ff_b1, hb, D, FF, 0);
    gemm8_bt<0, 4, 2><<<dim3(256), blk8, LDS8, stream>>>(
        hb, w2b, ff_b2, tmpbf, FF, D, TSL);
    ln_res_kernel<4, 1><<<dim3(TN), blk, 0, stream>>>(
        xb, tmpbf, TSL, ln3_g, ln3_b, (float*)d_out, nullptr);
}

// Round 8
// 461.147 us; speedup vs baseline: 1.0728x; 1.0071x over previous
//
#include <hip/hip_runtime.h>

// ---------------------------------------------------------------------------
// DecoderBlock: x = LN1(x + SelfAttn(x));  x = LN2(x + CrossAttn(x, mem));
//               x = LN3(x + W2·relu(W1·x + b1) + b2)
// B=2, N=2048, M=1024, D=1024, H=16, Dh=64, FF=4096.
// R20 = R19 + gemm8 MFMA shape 16x16x32 -> 32x32x16:
//   - 32x32 ceiling 2495 TF vs 16x16's 2075 (m119, +20%)
//   - 32 MFMA/K-group vs 64 (half the issue slots, same FLOPs)
//   - identical staging/swizzle/barrier/vmcnt schedule (R16-proven);
//     ds_read pattern keeps the 2-way-free bank mapping (0 conflicts).
//   C/D layout [m74/m101]: col=lane&31, row=(reg&3)+8*(reg>>2)+4*(lane>>5).
//   Everything else: R19 (attn 128q 8-wave + Q-prescale + v_perm; 128x64
//   small GEMMs; XCD-regioned grids).
// ---------------------------------------------------------------------------

typedef __attribute__((ext_vector_type(8))) short bf16x8;    // 8 bf16 (4 VGPRs)
typedef __attribute__((ext_vector_type(4))) float f32x4;
typedef __attribute__((ext_vector_type(16))) float f32x16;   // 32x32 acc

__device__ __forceinline__ unsigned short f2bf(float f) {
    union { float f; unsigned int u; } v; v.f = f;
    unsigned int r = v.u + 0x7fffu + ((v.u >> 16) & 1u);   // RNE
    return (unsigned short)(r >> 16);
}
__device__ __forceinline__ float bf2f(unsigned short u) {
    union { unsigned int u; float f; } v; v.u = (unsigned int)u << 16;
    return v.f;
}
__device__ __forceinline__ unsigned int fbits(float f) {
    union { float f; unsigned int u; } v; v.f = f;
    return v.u;
}

// ------------------- fused fp32->bf16 conversion + bias concat -------------
struct ConvArgs {
    const float* src[12];
    unsigned short* dst[12];
    int blk_ofs[13];
    int n4[12];
    const float* bq; const float* bk; const float* bv;
    const float* ck; const float* cv;
    float* bqkv; float* bkvc;
};
__global__ __launch_bounds__(256) void conv_multi(ConvArgs a)
{
    int bid = blockIdx.x;
    if (bid >= a.blk_ofs[12]) {                  // bias-concat tail
        int i = (bid - a.blk_ofs[12]) * 256 + threadIdx.x;   // 0..5119
        if (i < 1024)       a.bqkv[i] = a.bq[i];
        else if (i < 2048)  a.bqkv[i] = a.bk[i - 1024];
        else if (i < 3072)  a.bqkv[i] = a.bv[i - 2048];
        else if (i < 4096)  a.bkvc[i - 3072] = a.ck[i - 3072];
        else if (i < 5120)  a.bkvc[i - 3072] = a.cv[i - 4096];
        return;
    }
    int s = 0;
#pragma unroll
    for (int t = 0; t < 12; ++t) if (bid >= a.blk_ofs[t + 1]) s = t + 1;
    int i = (bid - a.blk_ofs[s]) * 256 + threadIdx.x;
    if (i >= a.n4[s]) return;
    float4 v = ((const float4*)a.src[s])[i];
    ushort4 o;
    o.x = f2bf(v.x); o.y = f2bf(v.y); o.z = f2bf(v.z); o.w = f2bf(v.w);
    ((ushort4*)a.dst[s])[i] = o;
}

// --------------------------- bf16 GEMM core (128x64, 2-phase) --------------
// Small-GEMM path: selfO/crossO (SK=2), crossQ (SK=1). 24KB LDS, 16x16x32.
template<int TM, int TN, int EPI, int SK>
__device__ __forceinline__ void gemm_body(
    unsigned short (*As)[64], unsigned short (*Bs)[64],
    const unsigned short* __restrict__ A, const unsigned short* __restrict__ W,
    const float* __restrict__ bias, unsigned short* __restrict__ out,
    int K, int Ncols, long slice_stride, int bid, int gx, int zslice)
{
    constexpr int AI = TM / 32;
    constexpr int BJ = TN / 32;

    const int tid  = threadIdx.x;
    const int lane = tid & 63;
    const int wave = tid >> 6;
    const int qd   = lane >> 4;
    const int l15  = lane & 15;
    const int wm   = (wave >> 1) * (TM / 2);
    const int wn   = (wave & 1) * (TN / 2);

    const int gpg = 8 * gx;                       // GROUP_M=8 swizzle
    const long m0 = (long)((bid / gpg) * 8 + (bid & 7)) * TM;
    const long n0 = (long)((bid % gpg) >> 3) * TN;

    f32x4 acc[AI][BJ] = {};

    const int srow = lane >> 3;
    const int scol = (((lane & 7) ^ srow)) * 8;   // XOR-swizzled group
    const unsigned short* Ag = A + (m0 + wave * (8 * AI) + srow) * (long)K + scol;
    const unsigned short* Wg = W + (n0 + wave * (8 * BJ) + srow) * (long)K + scol;

    const int ksl   = K / SK;
    const int kbase = (SK > 1) ? zslice * ksl : 0;

    for (int k0 = kbase; k0 < kbase + ksl; k0 += 64) {
#pragma unroll
        for (int c = 0; c < AI; ++c)
            __builtin_amdgcn_global_load_lds(
                (const __attribute__((address_space(1))) unsigned int*)(Ag + (long)c * 8 * K + k0),
                (__attribute__((address_space(3))) unsigned int*)((char*)&As[0][0] + (wave * AI + c) * 1024),
                16, 0, 0);
#pragma unroll
        for (int c = 0; c < BJ; ++c)
            __builtin_amdgcn_global_load_lds(
                (const __attribute__((address_space(1))) unsigned int*)(Wg + (long)c * 8 * K + k0),
                (__attribute__((address_space(3))) unsigned int*)((char*)&Bs[0][0] + (wave * BJ + c) * 1024),
                16, 0, 0);
        __syncthreads();
#pragma unroll
        for (int kk = 0; kk < 64; kk += 32) {
            const int pg = ((((kk >> 3) + qd)) ^ (l15 & 7)) * 8;  // de-swizzle
            bf16x8 af[AI], bw[BJ];
#pragma unroll
            for (int i = 0; i < AI; ++i)
                af[i] = *(const bf16x8*)&As[wm + i * 16 + l15][pg];
#pragma unroll
            for (int j = 0; j < BJ; ++j)
                bw[j] = *(const bf16x8*)&Bs[wn + j * 16 + l15][pg];
#pragma unroll
            for (int i = 0; i < AI; ++i)
#pragma unroll
                for (int j = 0; j < BJ; ++j)
                    acc[i][j] = __builtin_amdgcn_mfma_f32_16x16x32_bf16(
                        af[i], bw[j], acc[i][j], 0, 0, 0);
        }
        __syncthreads();
    }

    // epilogue. C/D layout: col = lane&15, row = quad*4 + reg  [m89-verified]
    unsigned short* op = out + ((SK > 1) ? (long)zslice * slice_stride : 0);
#pragma unroll
    for (int j = 0; j < BJ; ++j) {
        long col = n0 + wn + j * 16 + l15;
        float bv = (SK == 1 || zslice == 0) ? bias[col] : 0.f;
#pragma unroll
        for (int i = 0; i < AI; ++i) {
#pragma unroll
            for (int r = 0; r < 4; ++r) {
                long row = m0 + wm + i * 16 + qd * 4 + r;
                float v = acc[i][j][r] + bv;
                if (EPI == 1) v = (v > 0.f) ? v : 0.f;
                op[row * Ncols + col] = f2bf(v);
            }
        }
    }
}

template<int TM, int TN, int EPI, int SK>
__global__ __launch_bounds__(256) void gemm_bt(
    const unsigned short* __restrict__ A, const unsigned short* __restrict__ W,
    const float* __restrict__ bias, unsigned short* __restrict__ out,
    int K, int Ncols, long slice_stride)
{
    __shared__ unsigned short As[TM][64];
    __shared__ unsigned short Bs[TN][64];
    const int bid = blockIdx.y * gridDim.x + blockIdx.x;
    gemm_body<TM, TN, EPI, SK>(As, Bs, A, W, bias, out, K, Ncols, slice_stride,
                               bid, gridDim.x, (int)blockIdx.z);
}

// --------------------------- 256^2 2-barrier GEMM, 32x32x16 ----------------
// BM=BN=256, BK=64, 512 thr (8 waves, 2M x 4N), per-wave 128x64 output as
// 4x2 32x32 tiles (acc f32x16 x8 = 128 VGPR, same as before). LDS 128 KiB
// double-buffered; XOR-swizzle staging source + reads (2-way-free banks);
// per K-group: {pre-stage A(g+1)-tails | reads+16 MFMA i-tiles 0-1 | MID bar
// | stage g+2 into dead slots | reads+16 MFMA i-tiles 2-3 (B in regs) |
// vmcnt(6) + END bar}. Fragment maps: A row=lane&31 k=(lane>>5)*8+e;
// B col=lane&31 same k; D col=lane&31 row=(r&3)+8*(r>>2)+4*(lane>>5).
template<int EPI, int SK>
__device__ __forceinline__ void gemm8_body(
    unsigned short* Ab, unsigned short* Bb,
    const unsigned short* __restrict__ A, const unsigned short* __restrict__ W,
    const float* __restrict__ bias, unsigned short* __restrict__ out,
    int K, int Ncols, long slice_stride, int mb, int nb, int zslice)
{
    const int tid  = threadIdx.x;       // 0..511
    const int lane = tid & 63;
    const int wave = tid >> 6;          // 0..7
    const int l31  = lane & 31;
    const int hk   = lane >> 5;         // k-half (0: k0-7, 1: k8-15)
    const int l7   = lane & 7;
    const int wm   = (wave >> 2) * 128; // 2 M-waves
    const int wn   = (wave & 3) * 64;   // 4 N-waves

    const long m0 = (long)mb * 256;
    const long n0 = (long)nb * 256;

    const int ksl   = K / SK;
    const int kbase = (SK > 1) ? zslice * ksl : 0;
    const int NG    = ksl / 64;         // 16 for all call sites here

    f32x16 acc[4][2] = {};              // i-tile (rows wm+32i) x j-tile

    const int srow = tid >> 3;                       // 0..63
    const int sgrp = ((tid & 7) ^ (srow & 7)) * 8;
    const unsigned short* Ag = A + (m0 + srow) * (long)K + kbase + sgrp;
    const unsigned short* Wg = W + (n0 + srow) * (long)K + kbase + sgrp;

    auto stA = [&](int db, int r0, int kt) {
        __builtin_amdgcn_global_load_lds(
            (const __attribute__((address_space(1))) unsigned int*)(Ag + (long)r0 * K + kt * 64),
            (__attribute__((address_space(3))) unsigned int*)(Ab + db * 16384 + r0 * 64 + wave * 512),
            16, 0, 0);
    };
    auto stB = [&](int db, int r0, int kt) {
        __builtin_amdgcn_global_load_lds(
            (const __attribute__((address_space(1))) unsigned int*)(Wg + (long)r0 * K + kt * 64),
            (__attribute__((address_space(3))) unsigned int*)(Bb + db * 16384 + r0 * 64 + wave * 512),
            16, 0, 0);
    };
    // fragment read: global k-group g = kk*2 + hk at row; LDS holds group
    // p = g ^ (row&7); row&7 == lane&7 for all fragment rows (32-mult base).
    auto rdA = [&](int db, int row, int kk) -> bf16x8 {
        const int p = (((kk << 1) + hk) ^ l7) << 3;
        return *(const bf16x8*)(Ab + db * 16384 + row * 64 + p);
    };
    auto rdB = [&](int db, int row, int kk) -> bf16x8 {
        const int p = (((kk << 1) + hk) ^ l7) << 3;
        return *(const bf16x8*)(Bb + db * 16384 + row * 64 + p);
    };

    // ---- prologue: tile0 full (8) -> buf0; tile1 B + A-heads (6) -> buf1 --
#pragma unroll
    for (int h = 0; h < 4; ++h) stA(0, h * 64, 0);
#pragma unroll
    for (int h = 0; h < 4; ++h) stB(0, h * 64, 0);
    if (NG > 1) {
#pragma unroll
        for (int h = 0; h < 4; ++h) stB(1, h * 64, 1);
        stA(1, 0, 1); stA(1, 128, 1);
        asm volatile("s_waitcnt vmcnt(6)" ::: "memory");   // tile0 resident
    } else {
        asm volatile("s_waitcnt vmcnt(0)" ::: "memory");
    }
    __builtin_amdgcn_s_barrier();

    for (int g = 0; g < NG; ++g) {
        const int db = g & 1, ob = db ^ 1;
        bf16x8 af[2][4], bw[2][4];

        if (g + 1 < NG) { stA(ob, 64, g + 1); stA(ob, 192, g + 1); }

        // ---- h1: i-tiles 0-1 (A rows wm..wm+63) + B all; 16 MFMA ----
#pragma unroll
        for (int i = 0; i < 2; ++i)
#pragma unroll
            for (int kk = 0; kk < 4; ++kk)
                af[i][kk] = rdA(db, wm + i * 32 + l31, kk);
#pragma unroll
        for (int j = 0; j < 2; ++j)
#pragma unroll
            for (int kk = 0; kk < 4; ++kk)
                bw[j][kk] = rdB(db, wn + j * 32 + l31, kk);
        __builtin_amdgcn_s_setprio(1);
#pragma unroll
        for (int i = 0; i < 2; ++i)
#pragma unroll
            for (int j = 0; j < 2; ++j)
#pragma unroll
                for (int kk = 0; kk < 4; ++kk)
                    acc[i][j] = __builtin_amdgcn_mfma_f32_32x32x16_bf16(
                        af[i][kk], bw[j][kk], acc[i][j], 0, 0, 0);
        __builtin_amdgcn_s_setprio(0);
        __builtin_amdgcn_s_barrier();                      // MID

        if (g + 2 < NG) {
#pragma unroll
            for (int h = 0; h < 4; ++h) stB(db, h * 64, g + 2);
            stA(db, 0, g + 2); stA(db, 128, g + 2);
        }

        // ---- h2: i-tiles 2-3 (A rows wm+64..wm+127; B in regs); 16 MFMA ---
#pragma unroll
        for (int i = 0; i < 2; ++i)
#pragma unroll
            for (int kk = 0; kk < 4; ++kk)
                af[i][kk] = rdA(db, wm + 64 + i * 32 + l31, kk);
        __builtin_amdgcn_s_setprio(1);
#pragma unroll
        for (int i = 0; i < 2; ++i)
#pragma unroll
            for (int j = 0; j < 2; ++j)
#pragma unroll
                for (int kk = 0; kk < 4; ++kk)
                    acc[2 + i][j] = __builtin_amdgcn_mfma_f32_32x32x16_bf16(
                        af[i][kk], bw[j][kk], acc[2 + i][j], 0, 0, 0);
        __builtin_amdgcn_s_setprio(0);

        if (g + 2 < NG)      { asm volatile("s_waitcnt vmcnt(6)" ::: "memory"); }
        else if (g + 1 < NG) { asm volatile("s_waitcnt vmcnt(0)" ::: "memory"); }
        __builtin_amdgcn_s_barrier();
    }

    // ---- epilogue. 32x32 C/D: col=lane&31, row=(r&3)+8*(r>>2)+4*hk --------
    unsigned short* op = out + ((SK > 1) ? (long)zslice * slice_stride : 0);
#pragma unroll
    for (int j = 0; j < 2; ++j) {
        long col = n0 + wn + j * 32 + l31;
        float bv = (SK == 1 || zslice == 0) ? bias[col] : 0.f;
#pragma unroll
        for (int i = 0; i < 4; ++i) {
#pragma unroll
            for (int r = 0; r < 16; ++r) {
                long row = m0 + wm + i * 32 + (r & 3) + 8 * (r >> 2) + 4 * hk;
                float v = acc[i][j][r] + bv;
                if (EPI == 1) v = (v > 0.f) ? v : 0.f;
                op[row * Ncols + col] = f2bf(v);
            }
        }
    }
}

// MODE 1: FFN1 16m x 16n, per-XCD region 4m x 8n.
// MODE 2: FFN2 16m x 4n x 4z, z = xcd>>1, per-XCD-pair region 8m x 4n.
template<int EPI, int SK, int MODE>
__global__ __launch_bounds__(512) void gemm8_bt(
    const unsigned short* __restrict__ A, const unsigned short* __restrict__ W,
    const float* __restrict__ bias, unsigned short* __restrict__ out,
    int K, int Ncols, long slice_stride)
{
    extern __shared__ unsigned short smem[];
    const int bid = blockIdx.x;
    const int x = bid & 7;              // assumed hw XCD (round-robin)
    const int s = bid >> 3;             // 0..31
    int mb, nb, z = 0;
    if (MODE == 1) {
        mb = (x >> 1) * 4 + (s & 3);
        nb = (x & 1) * 8 + (s >> 2);
    } else {
        z  = x >> 1;
        mb = (x & 1) * 8 + (s & 7);
        nb = s >> 3;
    }
    gemm8_body<EPI, SK>(smem, smem + 32768, A, W, bias, out, K, Ncols,
                        slice_stride, mb, nb, z);
}

// selfQKV (192 blk, region 4m x 6n) + crossKV (64 blk, region 2m x 4n).
__global__ __launch_bounds__(512) void gemm8_dual(
    const unsigned short* A0, const unsigned short* W0, const float* b0,
    unsigned short* o0, int K0, int N0,
    const unsigned short* A1, const unsigned short* W1, const float* b1,
    unsigned short* o1, int K1, int N1)
{
    extern __shared__ unsigned short smem[];
    const int bid = blockIdx.x;
    const int x = bid & 7;
    const int s = bid >> 3;             // 0..31
    if (s < 24) {
        const int mb = (x >> 1) * 4 + (s & 3);
        const int nb = (x & 1) * 6 + (s >> 2);
        gemm8_body<0, 1>(smem, smem + 32768, A0, W0, b0, o0, K0, N0, 0, mb, nb, 0);
    } else {
        const int t = s - 24;           // 0..7
        const int mb = (x >> 1) * 2 + (t & 1);
        const int nb = (x & 1) * 4 + (t >> 1);
        gemm8_body<0, 1>(smem, smem + 32768, A1, W1, b1, o1, K1, N1, 0, mb, nb, 0);
    }
}

// --------------------------- flash attention (MFMA, 8-wave, 128q) ----------
// R19: q-tile 128 (8 waves); waves 0-3 stage V, waves 4-7 stage K. Ks/Vs/Ps
// XOR-swizzled (0 conflicts), Q pre-scaled by SCL (exp2 direct), v_perm pack.
__global__ __launch_bounds__(512) void attn_kernel(
    const unsigned short* __restrict__ Qb, int q_stride,
    const unsigned short* __restrict__ KVb, int kv_stride, int koff, int voff,
    unsigned short* __restrict__ O,
    int Nq, int Mk, int causal)
{
    __shared__ unsigned short Ks[64][64];
    __shared__ unsigned short Vs[64][64];
    __shared__ unsigned short Ps[8][16][64];

    const int tid  = threadIdx.x;       // 0..511
    const int lane = tid & 63;
    const int wave = tid >> 6;          // 0..7
    const int qd   = lane >> 4;
    const int l15  = lane & 15;
    const int l7   = l15 & 7;
    const int h    = blockIdx.y;
    const int b    = blockIdx.z;
    int jq = blockIdx.x;
    if (causal && (b & 1)) jq = gridDim.x - 1 - jq;
    const int q0 = jq * 128;
    const int tb = q0 + wave * 16;

    const float SCL = 0.125f * 1.44269504f;

    bf16x8 aq0, aq1;
    {
        const unsigned short* qp =
            Qb + (long)(b * Nq + tb + l15) * q_stride + h * 64 + qd * 8;
        aq0 = *(const bf16x8*)qp;
        aq1 = *(const bf16x8*)(qp + 32);
#pragma unroll
        for (int j = 0; j < 8; ++j) {
            aq0[j] = (short)f2bf(bf2f((unsigned short)aq0[j]) * SCL);
            aq1[j] = (short)f2bf(bf2f((unsigned short)aq1[j]) * SCL);
        }
    }

    float lpart[4] = {};
    f32x4 oacc[4] = {};

    // staging roles: tid<256 -> V, tid>=256 -> K
    const bool vrole = (tid < 256);
    const int vt   = tid & 255;
    const int vj   = vt & 31;
    const int va_k = (vj & 15) + ((vj & 16) << 1);
    const int vfg  = (vt >> 5) * 8;                      // 0..56
    const int vpc  = (va_k & 15) * 4 + (va_k >> 4);      // even => u32-aligned
    const int krow  = vt >> 3;                           // 0..31
    const int kcol  = (vt & 7) * 8;
    const int kcolS = (((vt & 7) ^ (krow & 7))) * 8;     // (krow+32)&7 == krow&7

    const unsigned short* Kg = KVb + (long)b * Mk * kv_stride + koff + h * 64;
    const unsigned short* Vg = KVb + (long)b * Mk * kv_stride + voff + h * 64;

    bf16x8 r0, r1;   // vrole: vra/vrb; krole: kr0/kr1
    auto prefetch = [&](int k0) {
        if (vrole) {
            const unsigned short* v0 = Vg + (long)(k0 + va_k) * kv_stride + vfg;
            r0 = *(const bf16x8*)v0;
            r1 = *(const bf16x8*)(v0 + 16 * kv_stride);
        } else {
            r0 = *(const bf16x8*)(Kg + (long)(k0 + krow) * kv_stride + kcol);
            r1 = *(const bf16x8*)(Kg + (long)(k0 + krow + 32) * kv_stride + kcol);
        }
    };

    const int nk = causal ? (q0 + 128) : Mk;
    prefetch(0);

    for (int k0 = 0; k0 < nk; k0 += 64) {
        __syncthreads();
        if (vrole) {
            const unsigned int* pa = (const unsigned int*)&r0;
            const unsigned int* pb = (const unsigned int*)&r1;
#pragma unroll
            for (int w2 = 0; w2 < 4; ++w2) {
                unsigned int d0 = __builtin_amdgcn_perm(pb[w2], pa[w2], 0x05040100u);
                unsigned int d1 = __builtin_amdgcn_perm(pb[w2], pa[w2], 0x07060302u);
                const int rr0 = vfg + 2 * w2, rr1 = rr0 + 1;
                *(unsigned int*)&Vs[rr0][vpc ^ ((rr0 & 7) << 3)] = d0;
                *(unsigned int*)&Vs[rr1][vpc ^ ((rr1 & 7) << 3)] = d1;
            }
        } else {
            *(bf16x8*)&Ks[krow][kcolS]      = r0;
            *(bf16x8*)&Ks[krow + 32][kcolS] = r1;
        }
        if (k0 + 64 < nk) prefetch(k0 + 64);
        __syncthreads();

        if (!causal || (k0 <= tb + 15)) {
            bf16x8 bk[4][2];
#pragma unroll
            for (int kt = 0; kt < 4; ++kt)
#pragma unroll
                for (int c = 0; c < 2; ++c)
                    bk[kt][c] = *(const bf16x8*)&Ks[kt * 16 + l15][((c * 4 + qd) ^ l7) * 8];
            f32x4 s[4];
#pragma unroll
            for (int kt = 0; kt < 4; ++kt) {
                f32x4 z = {};
                z = __builtin_amdgcn_mfma_f32_16x16x32_bf16(aq0, bk[kt][0], z, 0, 0, 0);
                z = __builtin_amdgcn_mfma_f32_16x16x32_bf16(aq1, bk[kt][1], z, 0, 0, 0);
                s[kt] = z;
            }
            const bool needmask = causal && (k0 + 63 > tb);
#pragma unroll
            for (int r = 0; r < 4; ++r) {
                const int qg = tb + qd * 4 + r;
                float e[4];
#pragma unroll
                for (int kt = 0; kt < 4; ++kt) {
                    float ev = __builtin_amdgcn_exp2f(s[kt][r]);
                    if (needmask && (k0 + kt * 16 + l15 > qg)) ev = 0.f;
                    e[kt] = ev;
                }
                lpart[r] += (e[0] + e[1]) + (e[2] + e[3]);
                unsigned int lo = __builtin_amdgcn_perm(fbits(e[1]), fbits(e[0]), 0x07060302u);
                unsigned int hi = __builtin_amdgcn_perm(fbits(e[3]), fbits(e[2]), 0x07060302u);
                uint2 pk; pk.x = lo; pk.y = hi;
                const int prow = qd * 4 + r;
                *(uint2*)&Ps[wave][prow][(l15 * 4) ^ ((prow & 7) << 3)] = pk;
            }
            bf16x8 bv[4][2];
#pragma unroll
            for (int dt = 0; dt < 4; ++dt)
#pragma unroll
                for (int c = 0; c < 2; ++c)
                    bv[dt][c] = *(const bf16x8*)&Vs[dt * 16 + l15][((c * 4 + qd) ^ l7) * 8];
            bf16x8 ap0 = *(const bf16x8*)&Ps[wave][l15][(qd ^ l7) * 8];
            bf16x8 ap1 = *(const bf16x8*)&Ps[wave][l15][((4 + qd) ^ l7) * 8];
#pragma unroll
            for (int dt = 0; dt < 4; ++dt) {
                oacc[dt] = __builtin_amdgcn_mfma_f32_16x16x32_bf16(
                    ap0, bv[dt][0], oacc[dt], 0, 0, 0);
                oacc[dt] = __builtin_amdgcn_mfma_f32_16x16x32_bf16(
                    ap1, bv[dt][1], oacc[dt], 0, 0, 0);
            }
        }
    }

#pragma unroll
    for (int r = 0; r < 4; ++r) {
        float l = lpart[r];
        l += __shfl_xor(l, 1);
        l += __shfl_xor(l, 2);
        l += __shfl_xor(l, 4);
        l += __shfl_xor(l, 8);
        float inv = 1.f / l;
        long row = (long)(b * Nq + tb + qd * 4 + r);
#pragma unroll
        for (int dt = 0; dt < 4; ++dt)
            O[row * 1024 + h * 64 + dt * 16 + l15] = f2bf(oacc[dt][r] * inv);
    }
}

// --------------------------- residual + LayerNorm --------------------------
template<int ND, int RESBF>
__global__ __launch_bounds__(256) void ln_res_kernel(
    const void* __restrict__ res, const unsigned short* __restrict__ delta,
    long dstride, const float* __restrict__ g, const float* __restrict__ beta,
    float* __restrict__ yout, unsigned short* __restrict__ ybf)
{
    __shared__ float red[8];
    const int row = blockIdx.x;
    const int tid = threadIdx.x;
    const long base = (long)row * 1024 + tid * 4;
    float v0, v1, v2, v3;
    if (RESBF) {
        ushort4 a = *(const ushort4*)((const unsigned short*)res + base);
        v0 = bf2f(a.x); v1 = bf2f(a.y); v2 = bf2f(a.z); v3 = bf2f(a.w);
    } else {
        float4 a = *(const float4*)((const float*)res + base);
        v0 = a.x; v1 = a.y; v2 = a.z; v3 = a.w;
    }
#pragma unroll
    for (int t = 0; t < ND; ++t) {
        ushort4 d = *(const ushort4*)(delta + t * dstride + base);
        v0 += bf2f(d.x); v1 += bf2f(d.y); v2 += bf2f(d.z); v3 += bf2f(d.w);
    }
    float s  = v0 + v1 + v2 + v3;
    float ss = v0 * v0 + v1 * v1 + v2 * v2 + v3 * v3;
#pragma unroll
    for (int off = 1; off < 64; off <<= 1) {
        s  += __shfl_xor(s, off);
        ss += __shfl_xor(ss, off);
    }
    const int wave = tid >> 6;
    if ((tid & 63) == 0) { red[wave] = s; red[4 + wave] = ss; }
    __syncthreads();
    float st  = red[0] + red[1] + red[2] + red[3];
    float sst = red[4] + red[5] + red[6] + red[7];
    float mean = st * (1.f / 1024.f);
    float var  = sst * (1.f / 1024.f) - mean * mean;
    float inv  = rsqrtf(var + 1e-5f);
    const int c = tid * 4;
    float y0 = (v0 - mean) * inv * g[c + 0] + beta[c + 0];
    float y1 = (v1 - mean) * inv * g[c + 1] + beta[c + 1];
    float y2 = (v2 - mean) * inv * g[c + 2] + beta[c + 2];
    float y3 = (v3 - mean) * inv * g[c + 3] + beta[c + 3];
    if (yout) *(float4*)(yout + base) = make_float4(y0, y1, y2, y3);
    if (ybf) {
        ushort4 o;
        o.x = f2bf(y0); o.y = f2bf(y1); o.z = f2bf(y2); o.w = f2bf(y3);
        *(ushort4*)(ybf + base) = o;
    }
}

// --------------------------- launch ----------------------------------------
extern "C" void kernel_launch(void* const* d_in, const int* in_sizes, int n_in,
                              void* d_out, int out_size, void* d_ws, size_t ws_size,
                              hipStream_t stream)
{
    const int B = 2, N = 2048, M = 1024, D = 1024, FF = 4096;
    const int TN = B * N;   // 4096
    const int TM = B * M;   // 2048
    const size_t MB = 1024 * 1024;

    const float* x     = (const float*)d_in[0];
    const float* mem   = (const float*)d_in[1];
    const float* sa_wq = (const float*)d_in[3];  const float* sa_bq = (const float*)d_in[4];
    const float* sa_wk = (const float*)d_in[5];  const float* sa_bk = (const float*)d_in[6];
    const float* sa_wv = (const float*)d_in[7];  const float* sa_bv = (const float*)d_in[8];
    const float* sa_wo = (const float*)d_in[9];  const float* sa_bo = (const float*)d_in[10];
    const float* ca_wq = (const float*)d_in[11]; const float* ca_bq = (const float*)d_in[12];
    const float* ca_wk = (const float*)d_in[13]; const float* ca_bk = (const float*)d_in[14];
    const float* ca_wv = (const float*)d_in[15]; const float* ca_bv = (const float*)d_in[16];
    const float* ca_wo = (const float*)d_in[17]; const float* ca_bo = (const float*)d_in[18];
    const float* ff_w1 = (const float*)d_in[19]; const float* ff_b1 = (const float*)d_in[20];
    const float* ff_w2 = (const float*)d_in[21]; const float* ff_b2 = (const float*)d_in[22];
    const float* ln1_g = (const float*)d_in[23]; const float* ln1_b = (const float*)d_in[24];
    const float* ln2_g = (const float*)d_in[25]; const float* ln2_b = (const float*)d_in[26];
    const float* ln3_g = (const float*)d_in[27]; const float* ln3_b = (const float*)d_in[28];

    char* w = (char*)d_ws;
    size_t off = 0;
    auto alloc = [&](size_t bytes) -> char* {
        char* p = w + off; off += (bytes + 255) & ~(size_t)255; return p;
    };

    unsigned short* xb   = (unsigned short*)alloc((size_t)TN * D * 2);   // 8 MB
    unsigned short* memb = (unsigned short*)alloc((size_t)TM * D * 2);   // 4 MB
    unsigned short* wqkv = (unsigned short*)alloc((size_t)3 * D * D * 2);// 6 MB
    unsigned short* wos  = (unsigned short*)alloc((size_t)D * D * 2);
    unsigned short* wqc  = (unsigned short*)alloc((size_t)D * D * 2);
    unsigned short* wkvc = (unsigned short*)alloc((size_t)2 * D * D * 2);// 4 MB
    unsigned short* woc  = (unsigned short*)alloc((size_t)D * D * 2);
    unsigned short* w1b  = (unsigned short*)alloc((size_t)FF * D * 2);   // 8 MB
    unsigned short* w2b  = (unsigned short*)alloc((size_t)D * FF * 2);   // 8 MB
    // big overlapped region (80 MB), phase-disjoint liveness (R10 layout):
    //   phase1: qkv [0,24)  kvb [32,40)  ab [24,32)
    //   phase2: qb [40,48)  kvb [32,40)  ab [24,32)
    //   phase3: hb [0,32)
    //   partials: tmpbf [48,80) (up to 4 x 8 MB bf16 slices)
    char* big = alloc((size_t)80 * MB);
    unsigned short* qkv   = (unsigned short*)big;
    unsigned short* ab    = (unsigned short*)(big + 24 * MB);
    unsigned short* kvb   = (unsigned short*)(big + 32 * MB);
    unsigned short* qb    = (unsigned short*)(big + 40 * MB);
    unsigned short* hb    = (unsigned short*)big;
    unsigned short* tmpbf = (unsigned short*)(big + 48 * MB);
    const long      TSL   = (long)TN * D;        // slice stride (elements)
    float* bqkv = (float*)alloc((size_t)3 * D * 4);
    float* bkvc = (float*)alloc((size_t)2 * D * 4);

    // ---- fused fp32->bf16 conversions + bias concat (one launch) ----
    ConvArgs ca;
    const float* srcs[12] = {x, mem, sa_wq, sa_wk, sa_wv, sa_wo,
                             ca_wq, ca_wk, ca_wv, ca_wo, ff_w1, ff_w2};
    unsigned short* dsts[12] = {xb, memb, wqkv, wqkv + (size_t)D * D,
                                wqkv + (size_t)2 * D * D, wos, wqc, wkvc,
                                wkvc + (size_t)D * D, woc, w1b, w2b};
    long ns[12] = {(long)TN * D, (long)TM * D, (long)D * D, (long)D * D,
                   (long)D * D, (long)D * D, (long)D * D, (long)D * D,
                   (long)D * D, (long)D * D, (long)FF * D, (long)D * FF};
    int total_blk = 0;
    for (int i = 0; i < 12; ++i) {
        ca.src[i] = srcs[i]; ca.dst[i] = dsts[i];
        ca.n4[i] = (int)(ns[i] / 4);
        ca.blk_ofs[i] = total_blk;
        total_blk += (ca.n4[i] + 255) / 256;
    }
    ca.blk_ofs[12] = total_blk;
    ca.bq = sa_bq; ca.bk = sa_bk; ca.bv = sa_bv; ca.ck = ca_bk; ca.cv = ca_bv;
    ca.bqkv = bqkv; ca.bkvc = bkvc;
    conv_multi<<<dim3(total_blk + 20), dim3(256), 0, stream>>>(ca);

    dim3 blk(256);
    dim3 blk8(512);
    const unsigned int LDS8 = 131072;   // 128 KiB dynamic LDS

    // ---- projections: selfQKV + crossKV, 256^2 2-barrier, XCD regions -----
    gemm8_dual<<<dim3(256), blk8, LDS8, stream>>>(
        xb,   wqkv, bqkv, qkv, D, 3 * D,
        memb, wkvc, bkvc, kvb, D, 2 * D);

    // ---- self-attention ----
    attn_kernel<<<dim3(N / 128, 16, B), blk8, 0, stream>>>(
        qkv, 3 * D, qkv, 3 * D, D, 2 * D, ab, N, N, 1);
    gemm_bt<128, 64, 0, 2><<<dim3(D / 64, TN / 128, 2), blk, 0, stream>>>(
        ab, wos, sa_bo, tmpbf, D, D, TSL);
    ln_res_kernel<2, 0><<<dim3(TN), blk, 0, stream>>>(
        x, tmpbf, TSL, ln1_g, ln1_b, nullptr, xb);

    // ---- cross-attention ----
    gemm_bt<128, 64, 0, 1><<<dim3(D / 64, TN / 128), blk, 0, stream>>>(
        xb, wqc, ca_bq, qb, D, D, 0);
    attn_kernel<<<dim3(N / 128, 16, B), blk8, 0, stream>>>(
        qb, D, kvb, 2 * D, 0, D, ab, N, M, 0);
    gemm_bt<128, 64, 0, 2><<<dim3(D / 64, TN / 128, 2), blk, 0, stream>>>(
        ab, woc, ca_bo, tmpbf, D, D, TSL);
    ln_res_kernel<2, 1><<<dim3(TN), blk, 0, stream>>>(
        xb, tmpbf, TSL, ln2_g, ln2_b, nullptr, xb);

    // ---- FFN ----
    gemm8_bt<1, 1, 1><<<dim3(256), blk8, LDS8, stream>>>(
        xb, w1b, ff_b1, hb, D, FF, 0);
    gemm8_bt<0, 4, 2><<<dim3(256), blk8, LDS8, stream>>>(
        hb, w2b, ff_b2, tmpbf, FF, D, TSL);
    ln_res_kernel<4, 1><<<dim3(TN), blk, 0, stream>>>(
        xb, tmpbf, TSL, ln3_g, ln3_b, (float*)d_out, nullptr);
}

// Round 9
// 459.438 us; speedup vs baseline: 1.0768x; 1.0037x over previous
//
#include <hip/hip_runtime.h>

// ---------------------------------------------------------------------------
// DecoderBlock: x = LN1(x + SelfAttn(x));  x = LN2(x + CrossAttn(x, mem));
//               x = LN3(x + W2·relu(W1·x + b1) + b2)
// B=2, N=2048, M=1024, D=1024, H=16, Dh=64, FF=4096.
// R21 = R20 (461.1us) + attn K/V LDS double-buffer:
//   old per-tile: {barrier -> LDS write -> barrier -> compute}
//   new per-tile: {write t+1 -> other buf || prefetch t+2 || compute t ->
//                  single barrier}  (ds_writes drain at the barrier,
//                  overlapping compute; one barrier/tile instead of two).
//   LDS 32->48KB; grid = 2 blocks/CU either way (512 blocks) -> occupancy
//   unchanged. GEMMs untouched (R20's 32x32 gemm8: micro-surgery declared
//   exhausted -- 3 schedules x 2 shapes all ~700 TF, barrier-lockstep bound;
//   32x32 4-way read conflict is structural but still net-faster than 16x16).
// ---------------------------------------------------------------------------

typedef __attribute__((ext_vector_type(8))) short bf16x8;    // 8 bf16 (4 VGPRs)
typedef __attribute__((ext_vector_type(4))) float f32x4;
typedef __attribute__((ext_vector_type(16))) float f32x16;   // 32x32 acc

__device__ __forceinline__ unsigned short f2bf(float f) {
    union { float f; unsigned int u; } v; v.f = f;
    unsigned int r = v.u + 0x7fffu + ((v.u >> 16) & 1u);   // RNE
    return (unsigned short)(r >> 16);
}
__device__ __forceinline__ float bf2f(unsigned short u) {
    union { unsigned int u; float f; } v; v.u = (unsigned int)u << 16;
    return v.f;
}
__device__ __forceinline__ unsigned int fbits(float f) {
    union { float f; unsigned int u; } v; v.f = f;
    return v.u;
}

// ------------------- fused fp32->bf16 conversion + bias concat -------------
struct ConvArgs {
    const float* src[12];
    unsigned short* dst[12];
    int blk_ofs[13];
    int n4[12];
    const float* bq; const float* bk; const float* bv;
    const float* ck; const float* cv;
    float* bqkv; float* bkvc;
};
__global__ __launch_bounds__(256) void conv_multi(ConvArgs a)
{
    int bid = blockIdx.x;
    if (bid >= a.blk_ofs[12]) {                  // bias-concat tail
        int i = (bid - a.blk_ofs[12]) * 256 + threadIdx.x;   // 0..5119
        if (i < 1024)       a.bqkv[i] = a.bq[i];
        else if (i < 2048)  a.bqkv[i] = a.bk[i - 1024];
        else if (i < 3072)  a.bqkv[i] = a.bv[i - 2048];
        else if (i < 4096)  a.bkvc[i - 3072] = a.ck[i - 3072];
        else if (i < 5120)  a.bkvc[i - 3072] = a.cv[i - 4096];
        return;
    }
    int s = 0;
#pragma unroll
    for (int t = 0; t < 12; ++t) if (bid >= a.blk_ofs[t + 1]) s = t + 1;
    int i = (bid - a.blk_ofs[s]) * 256 + threadIdx.x;
    if (i >= a.n4[s]) return;
    float4 v = ((const float4*)a.src[s])[i];
    ushort4 o;
    o.x = f2bf(v.x); o.y = f2bf(v.y); o.z = f2bf(v.z); o.w = f2bf(v.w);
    ((ushort4*)a.dst[s])[i] = o;
}

// --------------------------- bf16 GEMM core (128x64, 2-phase) --------------
// Small-GEMM path: selfO/crossO (SK=2), crossQ (SK=1). 24KB LDS, 16x16x32.
template<int TM, int TN, int EPI, int SK>
__device__ __forceinline__ void gemm_body(
    unsigned short (*As)[64], unsigned short (*Bs)[64],
    const unsigned short* __restrict__ A, const unsigned short* __restrict__ W,
    const float* __restrict__ bias, unsigned short* __restrict__ out,
    int K, int Ncols, long slice_stride, int bid, int gx, int zslice)
{
    constexpr int AI = TM / 32;
    constexpr int BJ = TN / 32;

    const int tid  = threadIdx.x;
    const int lane = tid & 63;
    const int wave = tid >> 6;
    const int qd   = lane >> 4;
    const int l15  = lane & 15;
    const int wm   = (wave >> 1) * (TM / 2);
    const int wn   = (wave & 1) * (TN / 2);

    const int gpg = 8 * gx;                       // GROUP_M=8 swizzle
    const long m0 = (long)((bid / gpg) * 8 + (bid & 7)) * TM;
    const long n0 = (long)((bid % gpg) >> 3) * TN;

    f32x4 acc[AI][BJ] = {};

    const int srow = lane >> 3;
    const int scol = (((lane & 7) ^ srow)) * 8;   // XOR-swizzled group
    const unsigned short* Ag = A + (m0 + wave * (8 * AI) + srow) * (long)K + scol;
    const unsigned short* Wg = W + (n0 + wave * (8 * BJ) + srow) * (long)K + scol;

    const int ksl   = K / SK;
    const int kbase = (SK > 1) ? zslice * ksl : 0;

    for (int k0 = kbase; k0 < kbase + ksl; k0 += 64) {
#pragma unroll
        for (int c = 0; c < AI; ++c)
            __builtin_amdgcn_global_load_lds(
                (const __attribute__((address_space(1))) unsigned int*)(Ag + (long)c * 8 * K + k0),
                (__attribute__((address_space(3))) unsigned int*)((char*)&As[0][0] + (wave * AI + c) * 1024),
                16, 0, 0);
#pragma unroll
        for (int c = 0; c < BJ; ++c)
            __builtin_amdgcn_global_load_lds(
                (const __attribute__((address_space(1))) unsigned int*)(Wg + (long)c * 8 * K + k0),
                (__attribute__((address_space(3))) unsigned int*)((char*)&Bs[0][0] + (wave * BJ + c) * 1024),
                16, 0, 0);
        __syncthreads();
#pragma unroll
        for (int kk = 0; kk < 64; kk += 32) {
            const int pg = ((((kk >> 3) + qd)) ^ (l15 & 7)) * 8;  // de-swizzle
            bf16x8 af[AI], bw[BJ];
#pragma unroll
            for (int i = 0; i < AI; ++i)
                af[i] = *(const bf16x8*)&As[wm + i * 16 + l15][pg];
#pragma unroll
            for (int j = 0; j < BJ; ++j)
                bw[j] = *(const bf16x8*)&Bs[wn + j * 16 + l15][pg];
#pragma unroll
            for (int i = 0; i < AI; ++i)
#pragma unroll
                for (int j = 0; j < BJ; ++j)
                    acc[i][j] = __builtin_amdgcn_mfma_f32_16x16x32_bf16(
                        af[i], bw[j], acc[i][j], 0, 0, 0);
        }
        __syncthreads();
    }

    // epilogue. C/D layout: col = lane&15, row = quad*4 + reg  [m89-verified]
    unsigned short* op = out + ((SK > 1) ? (long)zslice * slice_stride : 0);
#pragma unroll
    for (int j = 0; j < BJ; ++j) {
        long col = n0 + wn + j * 16 + l15;
        float bv = (SK == 1 || zslice == 0) ? bias[col] : 0.f;
#pragma unroll
        for (int i = 0; i < AI; ++i) {
#pragma unroll
            for (int r = 0; r < 4; ++r) {
                long row = m0 + wm + i * 16 + qd * 4 + r;
                float v = acc[i][j][r] + bv;
                if (EPI == 1) v = (v > 0.f) ? v : 0.f;
                op[row * Ncols + col] = f2bf(v);
            }
        }
    }
}

template<int TM, int TN, int EPI, int SK>
__global__ __launch_bounds__(256) void gemm_bt(
    const unsigned short* __restrict__ A, const unsigned short* __restrict__ W,
    const float* __restrict__ bias, unsigned short* __restrict__ out,
    int K, int Ncols, long slice_stride)
{
    __shared__ unsigned short As[TM][64];
    __shared__ unsigned short Bs[TN][64];
    const int bid = blockIdx.y * gridDim.x + blockIdx.x;
    gemm_body<TM, TN, EPI, SK>(As, Bs, A, W, bias, out, K, Ncols, slice_stride,
                               bid, gridDim.x, (int)blockIdx.z);
}

// --------------------------- 256^2 2-barrier GEMM, 32x32x16 ----------------
// (R20 version, unchanged.)
template<int EPI, int SK>
__device__ __forceinline__ void gemm8_body(
    unsigned short* Ab, unsigned short* Bb,
    const unsigned short* __restrict__ A, const unsigned short* __restrict__ W,
    const float* __restrict__ bias, unsigned short* __restrict__ out,
    int K, int Ncols, long slice_stride, int mb, int nb, int zslice)
{
    const int tid  = threadIdx.x;       // 0..511
    const int lane = tid & 63;
    const int wave = tid >> 6;          // 0..7
    const int l31  = lane & 31;
    const int hk   = lane >> 5;         // k-half (0: k0-7, 1: k8-15)
    const int l7   = lane & 7;
    const int wm   = (wave >> 2) * 128; // 2 M-waves
    const int wn   = (wave & 3) * 64;   // 4 N-waves

    const long m0 = (long)mb * 256;
    const long n0 = (long)nb * 256;

    const int ksl   = K / SK;
    const int kbase = (SK > 1) ? zslice * ksl : 0;
    const int NG    = ksl / 64;         // 16 for all call sites here

    f32x16 acc[4][2] = {};              // i-tile (rows wm+32i) x j-tile

    const int srow = tid >> 3;                       // 0..63
    const int sgrp = ((tid & 7) ^ (srow & 7)) * 8;
    const unsigned short* Ag = A + (m0 + srow) * (long)K + kbase + sgrp;
    const unsigned short* Wg = W + (n0 + srow) * (long)K + kbase + sgrp;

    auto stA = [&](int db, int r0, int kt) {
        __builtin_amdgcn_global_load_lds(
            (const __attribute__((address_space(1))) unsigned int*)(Ag + (long)r0 * K + kt * 64),
            (__attribute__((address_space(3))) unsigned int*)(Ab + db * 16384 + r0 * 64 + wave * 512),
            16, 0, 0);
    };
    auto stB = [&](int db, int r0, int kt) {
        __builtin_amdgcn_global_load_lds(
            (const __attribute__((address_space(1))) unsigned int*)(Wg + (long)r0 * K + kt * 64),
            (__attribute__((address_space(3))) unsigned int*)(Bb + db * 16384 + r0 * 64 + wave * 512),
            16, 0, 0);
    };
    // fragment read: global k-group g = kk*2 + hk at row; LDS holds group
    // p = g ^ (row&7); row&7 == lane&7 for all fragment rows (32-mult base).
    auto rdA = [&](int db, int row, int kk) -> bf16x8 {
        const int p = (((kk << 1) + hk) ^ l7) << 3;
        return *(const bf16x8*)(Ab + db * 16384 + row * 64 + p);
    };
    auto rdB = [&](int db, int row, int kk) -> bf16x8 {
        const int p = (((kk << 1) + hk) ^ l7) << 3;
        return *(const bf16x8*)(Bb + db * 16384 + row * 64 + p);
    };

    // ---- prologue: tile0 full (8) -> buf0; tile1 B + A-heads (6) -> buf1 --
#pragma unroll
    for (int h = 0; h < 4; ++h) stA(0, h * 64, 0);
#pragma unroll
    for (int h = 0; h < 4; ++h) stB(0, h * 64, 0);
    if (NG > 1) {
#pragma unroll
        for (int h = 0; h < 4; ++h) stB(1, h * 64, 1);
        stA(1, 0, 1); stA(1, 128, 1);
        asm volatile("s_waitcnt vmcnt(6)" ::: "memory");   // tile0 resident
    } else {
        asm volatile("s_waitcnt vmcnt(0)" ::: "memory");
    }
    __builtin_amdgcn_s_barrier();

    for (int g = 0; g < NG; ++g) {
        const int db = g & 1, ob = db ^ 1;
        bf16x8 af[2][4], bw[2][4];

        if (g + 1 < NG) { stA(ob, 64, g + 1); stA(ob, 192, g + 1); }

        // ---- h1: i-tiles 0-1 (A rows wm..wm+63) + B all; 16 MFMA ----
#pragma unroll
        for (int i = 0; i < 2; ++i)
#pragma unroll
            for (int kk = 0; kk < 4; ++kk)
                af[i][kk] = rdA(db, wm + i * 32 + l31, kk);
#pragma unroll
        for (int j = 0; j < 2; ++j)
#pragma unroll
            for (int kk = 0; kk < 4; ++kk)
                bw[j][kk] = rdB(db, wn + j * 32 + l31, kk);
        __builtin_amdgcn_s_setprio(1);
#pragma unroll
        for (int i = 0; i < 2; ++i)
#pragma unroll
            for (int j = 0; j < 2; ++j)
#pragma unroll
                for (int kk = 0; kk < 4; ++kk)
                    acc[i][j] = __builtin_amdgcn_mfma_f32_32x32x16_bf16(
                        af[i][kk], bw[j][kk], acc[i][j], 0, 0, 0);
        __builtin_amdgcn_s_setprio(0);
        __builtin_amdgcn_s_barrier();                      // MID

        if (g + 2 < NG) {
#pragma unroll
            for (int h = 0; h < 4; ++h) stB(db, h * 64, g + 2);
            stA(db, 0, g + 2); stA(db, 128, g + 2);
        }

        // ---- h2: i-tiles 2-3 (A rows wm+64..wm+127; B in regs); 16 MFMA ---
#pragma unroll
        for (int i = 0; i < 2; ++i)
#pragma unroll
            for (int kk = 0; kk < 4; ++kk)
                af[i][kk] = rdA(db, wm + 64 + i * 32 + l31, kk);
        __builtin_amdgcn_s_setprio(1);
#pragma unroll
        for (int i = 0; i < 2; ++i)
#pragma unroll
            for (int j = 0; j < 2; ++j)
#pragma unroll
                for (int kk = 0; kk < 4; ++kk)
                    acc[2 + i][j] = __builtin_amdgcn_mfma_f32_32x32x16_bf16(
                        af[i][kk], bw[j][kk], acc[2 + i][j], 0, 0, 0);
        __builtin_amdgcn_s_setprio(0);

        if (g + 2 < NG)      { asm volatile("s_waitcnt vmcnt(6)" ::: "memory"); }
        else if (g + 1 < NG) { asm volatile("s_waitcnt vmcnt(0)" ::: "memory"); }
        __builtin_amdgcn_s_barrier();
    }

    // ---- epilogue. 32x32 C/D: col=lane&31, row=(r&3)+8*(r>>2)+4*hk --------
    unsigned short* op = out + ((SK > 1) ? (long)zslice * slice_stride : 0);
#pragma unroll
    for (int j = 0; j < 2; ++j) {
        long col = n0 + wn + j * 32 + l31;
        float bv = (SK == 1 || zslice == 0) ? bias[col] : 0.f;
#pragma unroll
        for (int i = 0; i < 4; ++i) {
#pragma unroll
            for (int r = 0; r < 16; ++r) {
                long row = m0 + wm + i * 32 + (r & 3) + 8 * (r >> 2) + 4 * hk;
                float v = acc[i][j][r] + bv;
                if (EPI == 1) v = (v > 0.f) ? v : 0.f;
                op[row * Ncols + col] = f2bf(v);
            }
        }
    }
}

// MODE 1: FFN1 16m x 16n, per-XCD region 4m x 8n.
// MODE 2: FFN2 16m x 4n x 4z, z = xcd>>1, per-XCD-pair region 8m x 4n.
template<int EPI, int SK, int MODE>
__global__ __launch_bounds__(512) void gemm8_bt(
    const unsigned short* __restrict__ A, const unsigned short* __restrict__ W,
    const float* __restrict__ bias, unsigned short* __restrict__ out,
    int K, int Ncols, long slice_stride)
{
    extern __shared__ unsigned short smem[];
    const int bid = blockIdx.x;
    const int x = bid & 7;              // assumed hw XCD (round-robin)
    const int s = bid >> 3;             // 0..31
    int mb, nb, z = 0;
    if (MODE == 1) {
        mb = (x >> 1) * 4 + (s & 3);
        nb = (x & 1) * 8 + (s >> 2);
    } else {
        z  = x >> 1;
        mb = (x & 1) * 8 + (s & 7);
        nb = s >> 3;
    }
    gemm8_body<EPI, SK>(smem, smem + 32768, A, W, bias, out, K, Ncols,
                        slice_stride, mb, nb, z);
}

// selfQKV (192 blk, region 4m x 6n) + crossKV (64 blk, region 2m x 4n).
__global__ __launch_bounds__(512) void gemm8_dual(
    const unsigned short* A0, const unsigned short* W0, const float* b0,
    unsigned short* o0, int K0, int N0,
    const unsigned short* A1, const unsigned short* W1, const float* b1,
    unsigned short* o1, int K1, int N1)
{
    extern __shared__ unsigned short smem[];
    const int bid = blockIdx.x;
    const int x = bid & 7;
    const int s = bid >> 3;             // 0..31
    if (s < 24) {
        const int mb = (x >> 1) * 4 + (s & 3);
        const int nb = (x & 1) * 6 + (s >> 2);
        gemm8_body<0, 1>(smem, smem + 32768, A0, W0, b0, o0, K0, N0, 0, mb, nb, 0);
    } else {
        const int t = s - 24;           // 0..7
        const int mb = (x >> 1) * 2 + (t & 1);
        const int nb = (x & 1) * 4 + (t >> 1);
        gemm8_body<0, 1>(smem, smem + 32768, A1, W1, b1, o1, K1, N1, 0, mb, nb, 0);
    }
}

// --------------------------- flash attention (MFMA, 8-wave, 128q) ----------
// R21: K/V LDS double-buffered -- one barrier per 64-k tile; LDS write of
// tile t+1 overlaps compute of tile t (drains at the end barrier).
// Waves 0-3 stage V, 4-7 stage K; Ks/Vs/Ps XOR-swizzled (0 conflicts);
// Q pre-scaled by SCL (exp2 direct); v_perm packing.
__global__ __launch_bounds__(512) void attn_kernel(
    const unsigned short* __restrict__ Qb, int q_stride,
    const unsigned short* __restrict__ KVb, int kv_stride, int koff, int voff,
    unsigned short* __restrict__ O,
    int Nq, int Mk, int causal)
{
    __shared__ unsigned short Ks[2][64][64];
    __shared__ unsigned short Vs[2][64][64];
    __shared__ unsigned short Ps[8][16][64];

    const int tid  = threadIdx.x;       // 0..511
    const int lane = tid & 63;
    const int wave = tid >> 6;          // 0..7
    const int qd   = lane >> 4;
    const int l15  = lane & 15;
    const int l7   = l15 & 7;
    const int h    = blockIdx.y;
    const int b    = blockIdx.z;
    int jq = blockIdx.x;
    if (causal && (b & 1)) jq = gridDim.x - 1 - jq;
    const int q0 = jq * 128;
    const int tb = q0 + wave * 16;

    const float SCL = 0.125f * 1.44269504f;

    bf16x8 aq0, aq1;
    {
        const unsigned short* qp =
            Qb + (long)(b * Nq + tb + l15) * q_stride + h * 64 + qd * 8;
        aq0 = *(const bf16x8*)qp;
        aq1 = *(const bf16x8*)(qp + 32);
#pragma unroll
        for (int j = 0; j < 8; ++j) {
            aq0[j] = (short)f2bf(bf2f((unsigned short)aq0[j]) * SCL);
            aq1[j] = (short)f2bf(bf2f((unsigned short)aq1[j]) * SCL);
        }
    }

    float lpart[4] = {};
    f32x4 oacc[4] = {};

    // staging roles: tid<256 -> V, tid>=256 -> K
    const bool vrole = (tid < 256);
    const int vt   = tid & 255;
    const int vj   = vt & 31;
    const int va_k = (vj & 15) + ((vj & 16) << 1);
    const int vfg  = (vt >> 5) * 8;                      // 0..56
    const int vpc  = (va_k & 15) * 4 + (va_k >> 4);      // even => u32-aligned
    const int krow  = vt >> 3;                           // 0..31
    const int kcol  = (vt & 7) * 8;
    const int kcolS = (((vt & 7) ^ (krow & 7))) * 8;     // (krow+32)&7 == krow&7

    const unsigned short* Kg = KVb + (long)b * Mk * kv_stride + koff + h * 64;
    const unsigned short* Vg = KVb + (long)b * Mk * kv_stride + voff + h * 64;

    bf16x8 r0, r1;   // vrole: vra/vrb; krole: kr0/kr1
    auto prefetch = [&](int k0) {
        if (vrole) {
            const unsigned short* v0 = Vg + (long)(k0 + va_k) * kv_stride + vfg;
            r0 = *(const bf16x8*)v0;
            r1 = *(const bf16x8*)(v0 + 16 * kv_stride);
        } else {
            r0 = *(const bf16x8*)(Kg + (long)(k0 + krow) * kv_stride + kcol);
            r1 = *(const bf16x8*)(Kg + (long)(k0 + krow + 32) * kv_stride + kcol);
        }
    };
    auto writeKV = [&](int bs) {
        if (vrole) {
            const unsigned int* pa = (const unsigned int*)&r0;
            const unsigned int* pb = (const unsigned int*)&r1;
#pragma unroll
            for (int w2 = 0; w2 < 4; ++w2) {
                unsigned int d0 = __builtin_amdgcn_perm(pb[w2], pa[w2], 0x05040100u);
                unsigned int d1 = __builtin_amdgcn_perm(pb[w2], pa[w2], 0x07060302u);
                const int rr0 = vfg + 2 * w2, rr1 = rr0 + 1;
                *(unsigned int*)&Vs[bs][rr0][vpc ^ ((rr0 & 7) << 3)] = d0;
                *(unsigned int*)&Vs[bs][rr1][vpc ^ ((rr1 & 7) << 3)] = d1;
            }
        } else {
            *(bf16x8*)&Ks[bs][krow][kcolS]      = r0;
            *(bf16x8*)&Ks[bs][krow + 32][kcolS] = r1;
        }
    };

    const int nk = causal ? (q0 + 128) : Mk;
    const int nt = nk >> 6;             // 64-k tiles (nk is a multiple of 64)

    // prologue: tile0 -> buf0; prefetch tile1
    prefetch(0);
    writeKV(0);
    if (nt > 1) prefetch(64);
    __syncthreads();

    int cur = 0;
    for (int t = 0; t < nt; ++t) {
        const int k0 = t << 6;
        // write tile t+1 into the idle buffer; prefetch t+2 into regs.
        // Safe: prior barrier guarantees all waves done reading buf[1-cur]
        // (tile t-1). Writes drain at this iteration's end barrier.
        if (t + 1 < nt) {
            writeKV(cur ^ 1);
            if (t + 2 < nt) prefetch((t + 2) << 6);
        }

        if (!causal || (k0 <= tb + 15)) {
            bf16x8 bk[4][2];
#pragma unroll
            for (int kt = 0; kt < 4; ++kt)
#pragma unroll
                for (int c = 0; c < 2; ++c)
                    bk[kt][c] = *(const bf16x8*)&Ks[cur][kt * 16 + l15][((c * 4 + qd) ^ l7) * 8];
            f32x4 s[4];
#pragma unroll
            for (int kt = 0; kt < 4; ++kt) {
                f32x4 z = {};
                z = __builtin_amdgcn_mfma_f32_16x16x32_bf16(aq0, bk[kt][0], z, 0, 0, 0);
                z = __builtin_amdgcn_mfma_f32_16x16x32_bf16(aq1, bk[kt][1], z, 0, 0, 0);
                s[kt] = z;
            }
            const bool needmask = causal && (k0 + 63 > tb);
#pragma unroll
            for (int r = 0; r < 4; ++r) {
                const int qg = tb + qd * 4 + r;
                float e[4];
#pragma unroll
                for (int kt = 0; kt < 4; ++kt) {
                    float ev = __builtin_amdgcn_exp2f(s[kt][r]);
                    if (needmask && (k0 + kt * 16 + l15 > qg)) ev = 0.f;
                    e[kt] = ev;
                }
                lpart[r] += (e[0] + e[1]) + (e[2] + e[3]);
                unsigned int lo = __builtin_amdgcn_perm(fbits(e[1]), fbits(e[0]), 0x07060302u);
                unsigned int hi = __builtin_amdgcn_perm(fbits(e[3]), fbits(e[2]), 0x07060302u);
                uint2 pk; pk.x = lo; pk.y = hi;
                const int prow = qd * 4 + r;
                *(uint2*)&Ps[wave][prow][(l15 * 4) ^ ((prow & 7) << 3)] = pk;
            }
            bf16x8 bv[4][2];
#pragma unroll
            for (int dt = 0; dt < 4; ++dt)
#pragma unroll
                for (int c = 0; c < 2; ++c)
                    bv[dt][c] = *(const bf16x8*)&Vs[cur][dt * 16 + l15][((c * 4 + qd) ^ l7) * 8];
            bf16x8 ap0 = *(const bf16x8*)&Ps[wave][l15][(qd ^ l7) * 8];
            bf16x8 ap1 = *(const bf16x8*)&Ps[wave][l15][((4 + qd) ^ l7) * 8];
#pragma unroll
            for (int dt = 0; dt < 4; ++dt) {
                oacc[dt] = __builtin_amdgcn_mfma_f32_16x16x32_bf16(
                    ap0, bv[dt][0], oacc[dt], 0, 0, 0);
                oacc[dt] = __builtin_amdgcn_mfma_f32_16x16x32_bf16(
                    ap1, bv[dt][1], oacc[dt], 0, 0, 0);
            }
        }
        __syncthreads();
        cur ^= 1;
    }

#pragma unroll
    for (int r = 0; r < 4; ++r) {
        float l = lpart[r];
        l += __shfl_xor(l, 1);
        l += __shfl_xor(l, 2);
        l += __shfl_xor(l, 4);
        l += __shfl_xor(l, 8);
        float inv = 1.f / l;
        long row = (long)(b * Nq + tb + qd * 4 + r);
#pragma unroll
        for (int dt = 0; dt < 4; ++dt)
            O[row * 1024 + h * 64 + dt * 16 + l15] = f2bf(oacc[dt][r] * inv);
    }
}

// --------------------------- residual + LayerNorm --------------------------
template<int ND, int RESBF>
__global__ __launch_bounds__(256) void ln_res_kernel(
    const void* __restrict__ res, const unsigned short* __restrict__ delta,
    long dstride, const float* __restrict__ g, const float* __restrict__ beta,
    float* __restrict__ yout, unsigned short* __restrict__ ybf)
{
    __shared__ float red[8];
    const int row = blockIdx.x;
    const int tid = threadIdx.x;
    const long base = (long)row * 1024 + tid * 4;
    float v0, v1, v2, v3;
    if (RESBF) {
        ushort4 a = *(const ushort4*)((const unsigned short*)res + base);
        v0 = bf2f(a.x); v1 = bf2f(a.y); v2 = bf2f(a.z); v3 = bf2f(a.w);
    } else {
        float4 a = *(const float4*)((const float*)res + base);
        v0 = a.x; v1 = a.y; v2 = a.z; v3 = a.w;
    }
#pragma unroll
    for (int t = 0; t < ND; ++t) {
        ushort4 d = *(const ushort4*)(delta + t * dstride + base);
        v0 += bf2f(d.x); v1 += bf2f(d.y); v2 += bf2f(d.z); v3 += bf2f(d.w);
    }
    float s  = v0 + v1 + v2 + v3;
    float ss = v0 * v0 + v1 * v1 + v2 * v2 + v3 * v3;
#pragma unroll
    for (int off = 1; off < 64; off <<= 1) {
        s  += __shfl_xor(s, off);
        ss += __shfl_xor(ss, off);
    }
    const int wave = tid >> 6;
    if ((tid & 63) == 0) { red[wave] = s; red[4 + wave] = ss; }
    __syncthreads();
    float st  = red[0] + red[1] + red[2] + red[3];
    float sst = red[4] + red[5] + red[6] + red[7];
    float mean = st * (1.f / 1024.f);
    float var  = sst * (1.f / 1024.f) - mean * mean;
    float inv  = rsqrtf(var + 1e-5f);
    const int c = tid * 4;
    float y0 = (v0 - mean) * inv * g[c + 0] + beta[c + 0];
    float y1 = (v1 - mean) * inv * g[c + 1] + beta[c + 1];
    float y2 = (v2 - mean) * inv * g[c + 2] + beta[c + 2];
    float y3 = (v3 - mean) * inv * g[c + 3] + beta[c + 3];
    if (yout) *(float4*)(yout + base) = make_float4(y0, y1, y2, y3);
    if (ybf) {
        ushort4 o;
        o.x = f2bf(y0); o.y = f2bf(y1); o.z = f2bf(y2); o.w = f2bf(y3);
        *(ushort4*)(ybf + base) = o;
    }
}

// --------------------------- launch ----------------------------------------
extern "C" void kernel_launch(void* const* d_in, const int* in_sizes, int n_in,
                              void* d_out, int out_size, void* d_ws, size_t ws_size,
                              hipStream_t stream)
{
    const int B = 2, N = 2048, M = 1024, D = 1024, FF = 4096;
    const int TN = B * N;   // 4096
    const int TM = B * M;   // 2048
    const size_t MB = 1024 * 1024;

    const float* x     = (const float*)d_in[0];
    const float* mem   = (const float*)d_in[1];
    const float* sa_wq = (const float*)d_in[3];  const float* sa_bq = (const float*)d_in[4];
    const float* sa_wk = (const float*)d_in[5];  const float* sa_bk = (const float*)d_in[6];
    const float* sa_wv = (const float*)d_in[7];  const float* sa_bv = (const float*)d_in[8];
    const float* sa_wo = (const float*)d_in[9];  const float* sa_bo = (const float*)d_in[10];
    const float* ca_wq = (const float*)d_in[11]; const float* ca_bq = (const float*)d_in[12];
    const float* ca_wk = (const float*)d_in[13]; const float* ca_bk = (const float*)d_in[14];
    const float* ca_wv = (const float*)d_in[15]; const float* ca_bv = (const float*)d_in[16];
    const float* ca_wo = (const float*)d_in[17]; const float* ca_bo = (const float*)d_in[18];
    const float* ff_w1 = (const float*)d_in[19]; const float* ff_b1 = (const float*)d_in[20];
    const float* ff_w2 = (const float*)d_in[21]; const float* ff_b2 = (const float*)d_in[22];
    const float* ln1_g = (const float*)d_in[23]; const float* ln1_b = (const float*)d_in[24];
    const float* ln2_g = (const float*)d_in[25]; const float* ln2_b = (const float*)d_in[26];
    const float* ln3_g = (const float*)d_in[27]; const float* ln3_b = (const float*)d_in[28];

    char* w = (char*)d_ws;
    size_t off = 0;
    auto alloc = [&](size_t bytes) -> char* {
        char* p = w + off; off += (bytes + 255) & ~(size_t)255; return p;
    };

    unsigned short* xb   = (unsigned short*)alloc((size_t)TN * D * 2);   // 8 MB
    unsigned short* memb = (unsigned short*)alloc((size_t)TM * D * 2);   // 4 MB
    unsigned short* wqkv = (unsigned short*)alloc((size_t)3 * D * D * 2);// 6 MB
    unsigned short* wos  = (unsigned short*)alloc((size_t)D * D * 2);
    unsigned short* wqc  = (unsigned short*)alloc((size_t)D * D * 2);
    unsigned short* wkvc = (unsigned short*)alloc((size_t)2 * D * D * 2);// 4 MB
    unsigned short* woc  = (unsigned short*)alloc((size_t)D * D * 2);
    unsigned short* w1b  = (unsigned short*)alloc((size_t)FF * D * 2);   // 8 MB
    unsigned short* w2b  = (unsigned short*)alloc((size_t)D * FF * 2);   // 8 MB
    // big overlapped region (80 MB), phase-disjoint liveness (R10 layout):
    //   phase1: qkv [0,24)  kvb [32,40)  ab [24,32)
    //   phase2: qb [40,48)  kvb [32,40)  ab [24,32)
    //   phase3: hb [0,32)
    //   partials: tmpbf [48,80) (up to 4 x 8 MB bf16 slices)
    char* big = alloc((size_t)80 * MB);
    unsigned short* qkv   = (unsigned short*)big;
    unsigned short* ab    = (unsigned short*)(big + 24 * MB);
    unsigned short* kvb   = (unsigned short*)(big + 32 * MB);
    unsigned short* qb    = (unsigned short*)(big + 40 * MB);
    unsigned short* hb    = (unsigned short*)big;
    unsigned short* tmpbf = (unsigned short*)(big + 48 * MB);
    const long      TSL   = (long)TN * D;        // slice stride (elements)
    float* bqkv = (float*)alloc((size_t)3 * D * 4);
    float* bkvc = (float*)alloc((size_t)2 * D * 4);

    // ---- fused fp32->bf16 conversions + bias concat (one launch) ----
    ConvArgs ca;
    const float* srcs[12] = {x, mem, sa_wq, sa_wk, sa_wv, sa_wo,
                             ca_wq, ca_wk, ca_wv, ca_wo, ff_w1, ff_w2};
    unsigned short* dsts[12] = {xb, memb, wqkv, wqkv + (size_t)D * D,
                                wqkv + (size_t)2 * D * D, wos, wqc, wkvc,
                                wkvc + (size_t)D * D, woc, w1b, w2b};
    long ns[12] = {(long)TN * D, (long)TM * D, (long)D * D, (long)D * D,
                   (long)D * D, (long)D * D, (long)D * D, (long)D * D,
                   (long)D * D, (long)D * D, (long)FF * D, (long)D * FF};
    int total_blk = 0;
    for (int i = 0; i < 12; ++i) {
        ca.src[i] = srcs[i]; ca.dst[i] = dsts[i];
        ca.n4[i] = (int)(ns[i] / 4);
        ca.blk_ofs[i] = total_blk;
        total_blk += (ca.n4[i] + 255) / 256;
    }
    ca.blk_ofs[12] = total_blk;
    ca.bq = sa_bq; ca.bk = sa_bk; ca.bv = sa_bv; ca.ck = ca_bk; ca.cv = ca_bv;
    ca.bqkv = bqkv; ca.bkvc = bkvc;
    conv_multi<<<dim3(total_blk + 20), dim3(256), 0, stream>>>(ca);

    dim3 blk(256);
    dim3 blk8(512);
    const unsigned int LDS8 = 131072;   // 128 KiB dynamic LDS

    // ---- projections: selfQKV + crossKV, 256^2 2-barrier, XCD regions -----
    gemm8_dual<<<dim3(256), blk8, LDS8, stream>>>(
        xb,   wqkv, bqkv, qkv, D, 3 * D,
        memb, wkvc, bkvc, kvb, D, 2 * D);

    // ---- self-attention ----
    attn_kernel<<<dim3(N / 128, 16, B), blk8, 0, stream>>>(
        qkv, 3 * D, qkv, 3 * D, D, 2 * D, ab, N, N, 1);
    gemm_bt<128, 64, 0, 2><<<dim3(D / 64, TN / 128, 2), blk, 0, stream>>>(
        ab, wos, sa_bo, tmpbf, D, D, TSL);
    ln_res_kernel<2, 0><<<dim3(TN), blk, 0, stream>>>(
        x, tmpbf, TSL, ln1_g, ln1_b, nullptr, xb);

    // ---- cross-attention ----
    gemm_bt<128, 64, 0, 1><<<dim3(D / 64, TN / 128), blk, 0, stream>>>(
        xb, wqc, ca_bq, qb, D, D, 0);
    attn_kernel<<<dim3(N / 128, 16, B), blk8, 0, stream>>>(
        qb, D, kvb, 2 * D, 0, D, ab, N, M, 0);
    gemm_bt<128, 64, 0, 2><<<dim3(D / 64, TN / 128, 2), blk, 0, stream>>>(
        ab, woc, ca_bo, tmpbf, D, D, TSL);
    ln_res_kernel<2, 1><<<dim3(TN), blk, 0, stream>>>(
        xb, tmpbf, TSL, ln2_g, ln2_b, nullptr, xb);

    // ---- FFN ----
    gemm8_bt<1, 1, 1><<<dim3(256), blk8, LDS8, stream>>>(
        xb, w1b, ff_b1, hb, D, FF, 0);
    gemm8_bt<0, 4, 2><<<dim3(256), blk8, LDS8, stream>>>(
        hb, w2b, ff_b2, tmpbf, FF, D, TSL);
    ln_res_kernel<4, 1><<<dim3(TN), blk, 0, stream>>>(
        xb, tmpbf, TSL, ln3_g, ln3_b, (float*)d_out, nullptr);
}